// Round 11
// baseline (1302.613 us; speedup 1.0000x reference)
//
#include <hip/hip_runtime.h>

#define R_ 3
#define T_ 3
#define N_ 50000
#define OPS_ 24
#define E_ 400000
#define B_ 32
#define MAXDEG_ 8
#define QD_ 128
#define ED_ 128
#define H_ 128
#define G4_ (4*H_)   /* 512 */
#define HPAD 168     /* padded LDS h-row (bf16): 128 h + 25 one-hot + pad, 336 B */
#define PSLOTS 64    /* partial row-sum slots per (r,t) */

typedef unsigned short u16;
typedef __attribute__((ext_vector_type(8))) short bf16x8;   // 8 bf16 = 4 VGPRs
typedef __attribute__((ext_vector_type(4))) float f32x4;

#define BF16_ONE ((short)0x3F80)

__device__ __forceinline__ short f2bf(float f){
  union { float f; unsigned u; } v; v.f = f;
  unsigned r = v.u + 0x7fffu + ((v.u >> 16) & 1u);
  return (short)(r >> 16);
}
__device__ __forceinline__ float bf2f(u16 u){
  union { unsigned u; float f; } v; v.u = ((unsigned)u) << 16; return v.f;
}
__device__ __forceinline__ float frcp(float x){ return __builtin_amdgcn_rcpf(x); }
__device__ __forceinline__ float fsig(float x){ return frcp(1.0f + __expf(-x)); }
// tanh(x) = 2*sigmoid(2x) - 1
__device__ __forceinline__ float ftanh(float x){
  return __builtin_fmaf(2.0f, fsig(2.0f * x), -1.0f);
}

// ---------------- query BiLSTM + attention: one block per (r,b) ----------------
__global__ void qattn_kernel(const int* __restrict__ queries, const float* __restrict__ qemb,
    const float* __restrict__ qWih, const float* __restrict__ qWhh,
    const float* __restrict__ qbih, const float* __restrict__ qbhh,
    const float* __restrict__ qlinW, const float* __restrict__ qlinb,
    float* __restrict__ query_attn /* R,T,B,25 */)
{
  int r = blockIdx.x / B_;
  int b = blockIdx.x % B_;
  int tid = threadIdx.x;   // 256
  __shared__ float x[QD_];
  __shared__ float gx[G4_];
  __shared__ float h[H_], c[H_];
  __shared__ float gtmp[G4_];
  __shared__ float hh[2][T_][H_];
  __shared__ float lg[OPS_ + 1];

  int q = queries[b];
  if (tid < QD_) x[tid] = qemb[q * QD_ + tid];
  __syncthreads();

  for (int dir = 0; dir < 2; ++dir){
    const float* Wih = qWih + (size_t)(r * 2 + dir) * G4_ * QD_;
    const float* Whh = qWhh + (size_t)(r * 2 + dir) * G4_ * H_;
    const float* bih = qbih + (r * 2 + dir) * G4_;
    const float* bhh = qbhh + (r * 2 + dir) * G4_;
    for (int j = tid; j < G4_; j += 256){
      const float4* wr = (const float4*)(Wih + (size_t)j * QD_);
      float s = bih[j] + bhh[j];
      for (int k = 0; k < QD_ / 4; ++k){
        float4 wv = wr[k];
        s += wv.x * x[4*k] + wv.y * x[4*k+1] + wv.z * x[4*k+2] + wv.w * x[4*k+3];
      }
      gx[j] = s;
    }
    if (tid < H_){ h[tid] = 0.f; c[tid] = 0.f; }
    __syncthreads();
    for (int t = 0; t < T_; ++t){
      for (int j = tid; j < G4_; j += 256){
        const float4* wr = (const float4*)(Whh + (size_t)j * H_);
        float s = 0.f;
        for (int k = 0; k < H_ / 4; ++k){
          float4 wv = wr[k];
          s += wv.x * h[4*k] + wv.y * h[4*k+1] + wv.z * h[4*k+2] + wv.w * h[4*k+3];
        }
        gtmp[j] = gx[j] + s;
      }
      __syncthreads();
      if (tid < H_){
        float gi = gtmp[tid], gf = gtmp[tid + H_], gg = gtmp[tid + 2*H_], go = gtmp[tid + 3*H_];
        float cn = fsig(gf) * c[tid] + fsig(gi) * ftanh(gg);
        float hn = fsig(go) * ftanh(cn);
        c[tid] = cn; h[tid] = hn;
        hh[dir][t][tid] = hn;
      }
      __syncthreads();
    }
  }

  for (int t = 0; t < T_; ++t){
    if (tid < OPS_ + 1){
      const float* wr = qlinW + tid * (2 * H_);
      float s = qlinb[tid];
      for (int k = 0; k < H_; ++k) s += wr[k] * hh[0][t][k];
      for (int k = 0; k < H_; ++k) s += wr[H_ + k] * hh[1][T_ - 1 - t][k];
      lg[tid] = s;
    }
    __syncthreads();
    if (tid == 0){
      float m = -1e30f;
      for (int o = 0; o < OPS_ + 1; ++o) m = fmaxf(m, lg[o]);
      float sum = 0.f;
      for (int o = 0; o < OPS_ + 1; ++o){ float e = __expf(lg[o] - m); lg[o] = e; sum += e; }
      float inv = frcp(sum);
      for (int o = 0; o < OPS_ + 1; ++o) lg[o] *= inv;
    }
    __syncthreads();
    if (tid < OPS_ + 1) query_attn[((size_t)(r * T_ + t) * B_ + b) * (OPS_ + 1) + tid] = lg[tid];
    __syncthreads();
  }
}

// ------------- entity input projection table: proj[dir][deg(25)][512] -------------
__global__ void eproj_kernel(const float* __restrict__ eemb, const float* __restrict__ eWih,
                             const float* __restrict__ ebih, const float* __restrict__ ebhh,
                             float* __restrict__ proj)
{
  int idx = blockIdx.x * 256 + threadIdx.x;
  if (idx >= 2 * (OPS_ + 1) * G4_) return;
  int j = idx % G4_;
  int v = (idx / G4_) % (OPS_ + 1);
  int dir = idx / (G4_ * (OPS_ + 1));
  const float4* wr = (const float4*)(eWih + (size_t)(dir * G4_ + j) * ED_);
  const float4* er = (const float4*)(eemb + v * ED_);
  float s = ebih[dir * G4_ + j] + ebhh[dir * G4_ + j];
  for (int k = 0; k < ED_ / 4; ++k){
    float4 wv = wr[k], ev = er[k];
    s += wv.x * ev.x + wv.y * ev.y + wv.z * ev.z + wv.w * ev.w;
  }
  proj[idx] = s;
}

// ---- build B-operand buffers in MFMA-fragment order ----
__global__ void wbuild_kernel(const float* __restrict__ eWhh, const float* __restrict__ proj,
                              u16* __restrict__ wtile, u16* __restrict__ wonehot)
{
  int idx = blockIdx.x * 256 + threadIdx.x;    // 2*32*5*64*8 = 163840
  if (idx >= 2 * 32 * 5 * 64 * 8) return;
  int jj = idx & 7;
  int lane = (idx >> 3) & 63;
  int kc = (idx >> 9) % 5;
  int gtile = (idx / (8 * 64 * 5)) & 31;
  int dir = idx / (8 * 64 * 5 * 32);
  int row = lane >> 4, col = lane & 15;
  int j = gtile * 16 + col;
  if (kc < 4){
    int k = kc * 32 + row * 8 + jj;
    float v = eWhh[((size_t)dir * G4_ + j) * H_ + k];
    wtile[((((size_t)dir * 32 + gtile) * 4 + kc) * 64 + lane) * 8 + jj] = (u16)f2bf(v);
  } else {
    int vdeg = row * 8 + jj;   // 0..31
    float v = (vdeg <= OPS_) ? proj[(size_t)dir * (OPS_ + 1) * G4_ + (size_t)vdeg * G4_ + j] : 0.f;
    wonehot[(((size_t)dir * 32 + gtile) * 64 + lane) * 8 + jj] = (u16)f2bf(v);
  }
}

// ------ entity BiLSTM: 512 threads, 8 waves, 64 entities (round-10 structure) ------
__global__ __launch_bounds__(512) void elstm_kernel(
    const int* __restrict__ degs,
    const u16* __restrict__ wtile, const u16* __restrict__ wonehot,
    u16* __restrict__ houts /* 2,N,128 bf16 */)
{
  int tid = threadIdx.x;
  int lane = tid & 63;
  int w = tid >> 6;        // wave 0..7
  int q = w >> 2;          // quad 0..1
  int wq = w & 3;          // h-slice owner within quad
  int row = lane >> 4, col = lane & 15;
  int ebase = blockIdx.x * 64;

  __shared__ __align__(16) short wlds[32 * 4 * 64 * 8];  // 128 KB
  __shared__ __align__(16) short hl[64 * HPAD];          // 21 KB

  int degr[MAXDEG_];
  {
    int eg = ebase + (tid & 63); if (eg >= N_) eg = N_ - 1;
    #pragma unroll
    for (int d = 0; d < MAXDEG_; ++d) degr[d] = degs[eg * MAXDEG_ + d];
  }

  {
    const float4* src = (const float4*)wtile;
    float4* dst = (float4*)wlds;
    for (int i = tid; i < 8192; i += 512) dst[i] = src[i];
  }
  for (int i = tid; i < 64 * HPAD; i += 512) hl[i] = 0;
  __syncthreads();
  if (tid < 64) hl[tid * HPAD + H_ + degr[0]] = BF16_ONE;   // dir0 first tt=0
  __syncthreads();

  for (int dir = 0; dir < 2; ++dir){
    const u16* Woh = wonehot + (size_t)dir * 32 * 64 * 8;
    float cst[16];
    #pragma unroll
    for (int i = 0; i < 16; ++i) cst[i] = 0.f;

    for (int t = 0; t < MAXDEG_; ++t){
      int tt = dir ? (MAXDEG_ - 1 - t) : t;
      f32x4 acc[16];
      #pragma unroll
      for (int i = 0; i < 16; ++i) acc[i] = (f32x4){0.f, 0.f, 0.f, 0.f};

      #pragma unroll 1
      for (int kc = 0; kc < 4; ++kc){
        bf16x8 af0 = *(const bf16x8*)&hl[(q * 32 + col) * HPAD + kc * 32 + row * 8];
        bf16x8 af1 = *(const bf16x8*)&hl[(q * 32 + 16 + col) * HPAD + kc * 32 + row * 8];
        #pragma unroll
        for (int g8 = 0; g8 < 8; ++g8){
          int gtile = (g8 >> 1) * 8 + wq * 2 + (g8 & 1);
          bf16x8 bfr = *(const bf16x8*)&wlds[((gtile * 4 + kc) * 64 + lane) * 8];
          acc[g8 * 2 + 0] = __builtin_amdgcn_mfma_f32_16x16x32_bf16(af0, bfr, acc[g8 * 2 + 0], 0, 0, 0);
          acc[g8 * 2 + 1] = __builtin_amdgcn_mfma_f32_16x16x32_bf16(af1, bfr, acc[g8 * 2 + 1], 0, 0, 0);
        }
      }
      {
        bf16x8 af0 = *(const bf16x8*)&hl[(q * 32 + col) * HPAD + H_ + row * 8];
        bf16x8 af1 = *(const bf16x8*)&hl[(q * 32 + 16 + col) * HPAD + H_ + row * 8];
        #pragma unroll
        for (int g8 = 0; g8 < 8; ++g8){
          int gtile = (g8 >> 1) * 8 + wq * 2 + (g8 & 1);
          bf16x8 bfr = *(const bf16x8*)(Woh + ((size_t)gtile * 64 + lane) * 8);
          acc[g8 * 2 + 0] = __builtin_amdgcn_mfma_f32_16x16x32_bf16(af0, bfr, acc[g8 * 2 + 0], 0, 0, 0);
          acc[g8 * 2 + 1] = __builtin_amdgcn_mfma_f32_16x16x32_bf16(af1, bfr, acc[g8 * 2 + 1], 0, 0, 0);
        }
      }

      __syncthreads();

      #pragma unroll
      for (int mt = 0; mt < 2; ++mt){
        #pragma unroll
        for (int reg = 0; reg < 4; ++reg){
          int e = q * 32 + mt * 16 + row * 4 + reg;
          #pragma unroll
          for (int gt2 = 0; gt2 < 2; ++gt2){
            int j = wq * 32 + gt2 * 16 + col;
            float gi = acc[(0 + gt2) * 2 + mt][reg];
            float gf = acc[(2 + gt2) * 2 + mt][reg];
            float gg = acc[(4 + gt2) * 2 + mt][reg];
            float go = acc[(6 + gt2) * 2 + mt][reg];
            int ci = (mt * 4 + reg) * 2 + gt2;
            float cn = fsig(gf) * cst[ci] + fsig(gi) * ftanh(gg);
            float hn = fsig(go) * ftanh(cn);
            cst[ci] = cn;
            hl[e * HPAD + j] = f2bf(hn);
          }
        }
      }
      if (tid < 64){
        hl[tid * HPAD + H_ + degr[tt]] = 0;
        if (t < MAXDEG_ - 1){
          int ttn = dir ? (MAXDEG_ - 2 - t) : (t + 1);
          hl[tid * HPAD + H_ + degr[ttn]] = BF16_ONE;
        }
      }
      __syncthreads();
    }

    for (int i = tid; i < 64 * H_; i += 512){
      int e = i >> 7, k = i & 127;
      int n = ebase + e;
      if (n < N_) houts[(size_t)dir * N_ * H_ + (size_t)n * H_ + k] = (u16)hl[e * HPAD + k];
    }
    if (dir == 0){
      __syncthreads();
      const float4* src = (const float4*)(wtile + (size_t)32 * 4 * 64 * 8);
      float4* dst = (float4*)wlds;
      for (int i = tid; i < 8192; i += 512) dst[i] = src[i];
      for (int i = tid; i < 64 * HPAD; i += 512) hl[i] = 0;
      __syncthreads();
      if (tid < 64) hl[tid * HPAD + H_ + degr[MAXDEG_ - 1]] = BF16_ONE;
      __syncthreads();
    }
  }
}

// ------------- entity attention: 10 entities x 24 ops per block, LDS-staged -------------
__global__ void eattn_kernel(const u16* __restrict__ hf, const u16* __restrict__ hb,
                             const float* __restrict__ elinW, const float* __restrict__ elinb,
                             float* __restrict__ attn /* N,24 */)
{
  __shared__ float W[OPS_][257];
  __shared__ float hhs[10][263];
  __shared__ float lgs[10][OPS_];
  int tid = threadIdx.x;    // 240
  int n0 = blockIdx.x * 10;
  for (int i = tid; i < OPS_ * 256; i += 240) W[i >> 8][i & 255] = elinW[i];
  for (int i = tid; i < 10 * H_; i += 240){
    int nl = i >> 7, k = i & 127;
    int n = n0 + nl;
    if (n < N_){
      hhs[nl][k]        = bf2f(hf[(size_t)n * H_ + k]);
      hhs[nl][H_ + k]   = bf2f(hb[(size_t)n * H_ + k]);
    }
  }
  __syncthreads();
  int nl = tid / OPS_;
  int o  = tid - nl * OPS_;
  int n  = n0 + nl;
  if (n < N_){
    float s = elinb[o];
    #pragma unroll 4
    for (int k = 0; k < 2 * H_; ++k) s += W[o][k] * hhs[nl][k];
    lgs[nl][o] = s;
  }
  __syncthreads();
  if (n < N_){
    float m = -1e30f;
    for (int i = 0; i < OPS_; ++i) m = fmaxf(m, lgs[nl][i]);
    float sum = 0.f;
    for (int i = 0; i < OPS_; ++i) sum += __expf(lgs[nl][i] - m);
    attn[(size_t)n * OPS_ + o] = __expf(lgs[nl][o] - m) * frcp(sum);
  }
}

// ---------------- CSR build: incoming-edge lists per node ----------------
// fwd fact (rel,h,t): node t receives (src=h, rel);  rev: node h receives (src=t, rel+12)
__global__ void csr_count_kernel(const int* __restrict__ theads, const int* __restrict__ ttails,
                                 int* __restrict__ counts)
{
  int e = blockIdx.x * 256 + threadIdx.x;
  if (e < E_){
    atomicAdd(&counts[ttails[e]], 1);
    atomicAdd(&counts[theads[e]], 1);
  }
}

// single-block exclusive scan over counts[N_] -> rowptr[N_+1], cursor copy
__global__ void csr_scan_kernel(const int* __restrict__ counts, int* __restrict__ rowptr,
                                int* __restrict__ cursor)
{
  __shared__ int lsum[1024];
  int t = threadIdx.x;
  const int CH = (N_ + 1023) / 1024;   // 49
  int base = t * CH;
  int s = 0;
  for (int i = 0; i < CH; ++i){
    int idx = base + i;
    if (idx < N_) s += counts[idx];
  }
  lsum[t] = s;
  __syncthreads();
  for (int o = 1; o < 1024; o <<= 1){
    int u = (t >= o) ? lsum[t - o] : 0;
    __syncthreads();
    lsum[t] += u;
    __syncthreads();
  }
  int run = lsum[t] - s;   // exclusive prefix at chunk start
  for (int i = 0; i < CH; ++i){
    int idx = base + i;
    if (idx < N_){
      rowptr[idx] = run;
      cursor[idx] = run;
      run += counts[idx];
    }
  }
  if (t == 1023) rowptr[N_] = run;
}

// fill entries: ent.x = src | (rel' << 16), ent.y = bits(weight)
__global__ void csr_fill_kernel(const int* __restrict__ rels, const int* __restrict__ theads,
                                const int* __restrict__ ttails, const float* __restrict__ attn,
                                int* __restrict__ cursor, uint2* __restrict__ ents)
{
  int e = blockIdx.x * 256 + threadIdx.x;
  if (e < E_){
    int hh = theads[e], tt = ttails[e], rel = rels[e];
    float we = attn[(size_t)hh * OPS_ + rel];
    uint2 v1; v1.x = (unsigned)hh | ((unsigned)rel << 16);            v1.y = __float_as_uint(we);
    uint2 v2; v2.x = (unsigned)tt | ((unsigned)(rel + OPS_/2) << 16); v2.y = __float_as_uint(we);
    int p = atomicAdd(&cursor[tt], 1);
    ents[p] = v1;
    int qd = atomicAdd(&cursor[hh], 1);
    ents[qd] = v2;
  }
}

// ---------------- propagation (unnormalized u; scale-invariant) ----------------
__global__ void initu_kernel(const int* __restrict__ heads, float* __restrict__ u0)
{
  int idx = blockIdx.x * 256 + threadIdx.x;
  if (idx < N_ * B_){
    int b = idx & (B_ - 1);
    int n = idx >> 5;
    u0[idx] = (heads[b] == n) ? 1.0f : 0.0f;
  }
}

// atomic-free gather: half-wave = one node's 32 batch lanes.
// u_next[n,b] = qa24[b]*u[n,b] + sum_incoming qas[b][rel']*we*u[src,b]; fused row-sums.
__global__ __launch_bounds__(256) void gather_kernel(
    const float* __restrict__ ucur, float* __restrict__ unxt,
    const float* __restrict__ qa, const int* __restrict__ rowptr,
    const uint2* __restrict__ ents, float* __restrict__ partial /* PSLOTS x B */)
{
  __shared__ float qas[B_ * (OPS_ + 1)];
  __shared__ float red[B_];
  int tid = threadIdx.x;
  for (int i = tid; i < B_ * (OPS_ + 1); i += 256) qas[i] = qa[i];
  if (tid < B_) red[tid] = 0.f;
  __syncthreads();
  int b  = tid & 31;
  int nl = tid >> 5;           // 0..7
  float local = 0.f;
  for (int n0 = blockIdx.x * 8; n0 < N_; n0 += gridDim.x * 8){
    int n = n0 + nl;
    if (n < N_){
      float acc = ucur[(size_t)n * B_ + b] * qas[b * (OPS_ + 1) + OPS_];
      int beg = rowptr[n], end = rowptr[n + 1];
      for (int i = beg; i < end; ++i){
        uint2 ent = ents[i];                    // broadcast load (same addr across 32 lanes)
        int src = (int)(ent.x & 0xFFFFu);
        int rl  = (int)(ent.x >> 16);
        float we = __uint_as_float(ent.y);
        acc += qas[b * (OPS_ + 1) + rl] * we * ucur[(size_t)src * B_ + b];  // coalesced 128B
      }
      unxt[(size_t)n * B_ + b] = acc;
      local += acc;
    }
  }
  atomicAdd(&red[b], local);
  __syncthreads();
  if (tid < B_) atomicAdd(&partial[(blockIdx.x & (PSLOTS - 1)) * B_ + tid], red[tid]);
}

// logacc += u / rowsum(u)   (rowsum from the PSLOTS partials of the last gather)
__global__ void finalize_kernel(float* __restrict__ logacc, const float* __restrict__ u,
                                const float* __restrict__ partial)
{
  __shared__ float smem[8][B_];
  __shared__ float sinv[B_];
  int tid = threadIdx.x;
  {
    int b = tid & (B_ - 1), pr = tid >> 5;
    float s = 0.f;
    #pragma unroll
    for (int k = 0; k < 8; ++k) s += partial[(pr + 8 * k) * B_ + b];
    smem[pr][b] = s;
  }
  __syncthreads();
  if (tid < B_){
    float s = 0.f;
    #pragma unroll
    for (int k = 0; k < 8; ++k) s += smem[k][tid];
    sinv[tid] = frcp(fmaxf(1e-20f, s));
  }
  __syncthreads();
  int idx = blockIdx.x * 256 + tid;
  if (idx < N_ * B_)
    logacc[idx] += u[idx] * sinv[idx & (B_ - 1)];
}

// ------------- final transpose: acc (N,B) -> out (B,N), LDS-tiled -------------
__global__ void transpose_kernel(const float* __restrict__ acc, float* __restrict__ out)
{
  __shared__ float t[B_][72];
  int n0 = blockIdx.x * 64;
  int tid = threadIdx.x;
  for (int i = tid; i < 64 * B_; i += 256){
    int nl = i >> 5, b = i & 31;
    int n = n0 + nl;
    t[b][nl] = (n < N_) ? acc[(size_t)n * B_ + b] : 0.f;
  }
  __syncthreads();
  for (int i = tid; i < 64 * B_; i += 256){
    int b = i >> 6, nl = i & 63;
    int n = n0 + nl;
    if (n < N_) out[(size_t)b * N_ + n] = t[b][nl];
  }
}

extern "C" void kernel_launch(void* const* d_in, const int* in_sizes, int n_in,
                              void* d_out, int out_size, void* d_ws, size_t ws_size,
                              hipStream_t stream)
{
  const int*   queries = (const int*)d_in[0];
  const int*   heads   = (const int*)d_in[1];
  const int*   rels    = (const int*)d_in[2];
  const int*   t_heads = (const int*)d_in[3];
  const int*   t_tails = (const int*)d_in[4];
  const int*   edeg    = (const int*)d_in[5];
  const float* qemb    = (const float*)d_in[6];
  const float* eemb    = (const float*)d_in[7];
  const float* qWih    = (const float*)d_in[8];
  const float* qWhh    = (const float*)d_in[9];
  const float* qbih    = (const float*)d_in[10];
  const float* qbhh    = (const float*)d_in[11];
  const float* eWih    = (const float*)d_in[12];
  const float* eWhh    = (const float*)d_in[13];
  const float* ebih    = (const float*)d_in[14];
  const float* ebhh    = (const float*)d_in[15];
  const float* qlinW   = (const float*)d_in[16];
  const float* qlinb   = (const float*)d_in[17];
  const float* elinW   = (const float*)d_in[18];
  const float* elinb   = (const float*)d_in[19];
  float* out = (float*)d_out;

  char* ws = (char*)d_ws;
  size_t off = 0;
  auto alloc = [&](size_t bytes){ void* p = ws + off; off += (bytes + 255) & ~(size_t)255; return p; };
  // region (25.6 MB): houts during [elstm, eattn]; then u0/u1/logacc (3x6.4 MB) +
  // ents (6.4 MB, written by csr_fill AFTER eattn) reuse the same bytes.
  char*  region     = (char*) alloc((size_t)2 * N_ * H_ * 2);                // 25.6 MB
  u16*   houts      = (u16*)region;
  float* mem0       = (float*)region;
  float* mem1       = (float*)(region + (size_t)N_ * B_ * 4);
  float* logacc     = (float*)(region + (size_t)2 * N_ * B_ * 4);
  uint2* ents       = (uint2*)(region + (size_t)3 * N_ * B_ * 4);            // 6.4 MB (=2E*8)
  float* query_attn = (float*)alloc((size_t)R_ * T_ * B_ * (OPS_ + 1) * 4);  //  29 KB
  float* proj       = (float*)alloc((size_t)2 * (OPS_ + 1) * G4_ * 4);       // 102 KB
  u16*   wtile      = (u16*)  alloc((size_t)2 * 32 * 4 * 64 * 8 * 2);        // 256 KB
  u16*   wonehot    = (u16*)  alloc((size_t)2 * 32 * 64 * 8 * 2);            //  64 KB
  float* attn       = (float*)alloc((size_t)N_ * OPS_ * 4);                  // 4.8 MB
  int*   counts     = (int*)  alloc((size_t)(N_ + 1) * 4);                   // 200 KB
  int*   rowptr     = (int*)  alloc((size_t)(N_ + 1) * 4);                   // 200 KB
  int*   cursor     = (int*)  alloc((size_t)(N_ + 1) * 4);                   // 200 KB
  float* sumsP      = (float*)alloc((size_t)R_ * T_ * PSLOTS * B_ * 4);      // 73 KB
  // total ~32 MB

  hipMemsetAsync(sumsP, 0, (size_t)R_ * T_ * PSLOTS * B_ * 4, stream);
  hipMemsetAsync(counts, 0, (size_t)(N_ + 1) * 4, stream);

  qattn_kernel<<<R_ * B_, 256, 0, stream>>>(queries, qemb, qWih, qWhh, qbih, qbhh,
                                            qlinW, qlinb, query_attn);
  eproj_kernel<<<(2 * (OPS_ + 1) * G4_ + 255) / 256, 256, 0, stream>>>(eemb, eWih, ebih, ebhh, proj);
  wbuild_kernel<<<(2 * 32 * 5 * 64 * 8 + 255) / 256, 256, 0, stream>>>(eWhh, proj, wtile, wonehot);
  csr_count_kernel<<<(E_ + 255) / 256, 256, 0, stream>>>(t_heads, t_tails, counts);
  csr_scan_kernel<<<1, 1024, 0, stream>>>(counts, rowptr, cursor);
  elstm_kernel<<<(N_ + 63) / 64, 512, 0, stream>>>(edeg, wtile, wonehot, houts);
  eattn_kernel<<<(N_ + 9) / 10, 240, 0, stream>>>(houts, houts + (size_t)N_ * H_,
                                                  elinW, elinb, attn);
  // houts dead; region reused for ents + propagation buffers
  csr_fill_kernel<<<(E_ + 255) / 256, 256, 0, stream>>>(rels, t_heads, t_tails, attn, cursor, ents);
  hipMemsetAsync(logacc, 0, (size_t)N_ * B_ * 4, stream);

  const int NB_BLK = (N_ * B_ + 255) / 256;
  const int GA_BLK = (N_ + 7) / 8;   // 6250
  for (int r = 0; r < R_; ++r){
    initu_kernel<<<NB_BLK, 256, 0, stream>>>(heads, mem0);
    float* cur = mem0;
    float* nxt = mem1;
    float* lastP = nullptr;
    for (int t = 0; t < T_; ++t){
      const float* qa = query_attn + (size_t)(r * T_ + t) * B_ * (OPS_ + 1);
      float* pslot = sumsP + (size_t)(r * T_ + t) * PSLOTS * B_;
      gather_kernel<<<GA_BLK, 256, 0, stream>>>(cur, nxt, qa, rowptr, ents, pslot);
      lastP = pslot;
      float* tmp = cur; cur = nxt; nxt = tmp;
    }
    finalize_kernel<<<NB_BLK, 256, 0, stream>>>(logacc, cur, lastP);
  }
  transpose_kernel<<<(N_ + 63) / 64, 256, 0, stream>>>(logacc, out);
}

// Round 12
// 1140.005 us; speedup vs baseline: 1.1426x; 1.1426x over previous
//
#include <hip/hip_runtime.h>

#define R_ 3
#define T_ 3
#define N_ 50000
#define OPS_ 24
#define E_ 400000
#define B_ 32
#define MAXDEG_ 8
#define QD_ 128
#define ED_ 128
#define H_ 128
#define G4_ (4*H_)   /* 512 */
#define HPAD 168     /* padded LDS h-row (bf16): 128 h + 25 one-hot + pad, 336 B */
#define PSLOTS 64    /* partial row-sum slots per (r,t) */

typedef unsigned short u16;
typedef __attribute__((ext_vector_type(8))) short bf16x8;   // 8 bf16 = 4 VGPRs
typedef __attribute__((ext_vector_type(4))) float f32x4;

#define BF16_ONE ((short)0x3F80)

__device__ __forceinline__ short f2bf(float f){
  union { float f; unsigned u; } v; v.f = f;
  unsigned r = v.u + 0x7fffu + ((v.u >> 16) & 1u);
  return (short)(r >> 16);
}
__device__ __forceinline__ float bf2f(u16 u){
  union { unsigned u; float f; } v; v.u = ((unsigned)u) << 16; return v.f;
}
__device__ __forceinline__ float frcp(float x){ return __builtin_amdgcn_rcpf(x); }
__device__ __forceinline__ float fsig(float x){ return frcp(1.0f + __expf(-x)); }
// tanh(x) = 2*sigmoid(2x) - 1
__device__ __forceinline__ float ftanh(float x){
  return __builtin_fmaf(2.0f, fsig(2.0f * x), -1.0f);
}

// ---------------- query BiLSTM + attention: one block per (r,b) ----------------
__global__ void qattn_kernel(const int* __restrict__ queries, const float* __restrict__ qemb,
    const float* __restrict__ qWih, const float* __restrict__ qWhh,
    const float* __restrict__ qbih, const float* __restrict__ qbhh,
    const float* __restrict__ qlinW, const float* __restrict__ qlinb,
    float* __restrict__ query_attn /* R,T,B,25 */)
{
  int r = blockIdx.x / B_;
  int b = blockIdx.x % B_;
  int tid = threadIdx.x;   // 256
  __shared__ float x[QD_];
  __shared__ float gx[G4_];
  __shared__ float h[H_], c[H_];
  __shared__ float gtmp[G4_];
  __shared__ float hh[2][T_][H_];
  __shared__ float lg[OPS_ + 1];

  int q = queries[b];
  if (tid < QD_) x[tid] = qemb[q * QD_ + tid];
  __syncthreads();

  for (int dir = 0; dir < 2; ++dir){
    const float* Wih = qWih + (size_t)(r * 2 + dir) * G4_ * QD_;
    const float* Whh = qWhh + (size_t)(r * 2 + dir) * G4_ * H_;
    const float* bih = qbih + (r * 2 + dir) * G4_;
    const float* bhh = qbhh + (r * 2 + dir) * G4_;
    for (int j = tid; j < G4_; j += 256){
      const float4* wr = (const float4*)(Wih + (size_t)j * QD_);
      float s = bih[j] + bhh[j];
      for (int k = 0; k < QD_ / 4; ++k){
        float4 wv = wr[k];
        s += wv.x * x[4*k] + wv.y * x[4*k+1] + wv.z * x[4*k+2] + wv.w * x[4*k+3];
      }
      gx[j] = s;
    }
    if (tid < H_){ h[tid] = 0.f; c[tid] = 0.f; }
    __syncthreads();
    for (int t = 0; t < T_; ++t){
      for (int j = tid; j < G4_; j += 256){
        const float4* wr = (const float4*)(Whh + (size_t)j * H_);
        float s = 0.f;
        for (int k = 0; k < H_ / 4; ++k){
          float4 wv = wr[k];
          s += wv.x * h[4*k] + wv.y * h[4*k+1] + wv.z * h[4*k+2] + wv.w * h[4*k+3];
        }
        gtmp[j] = gx[j] + s;
      }
      __syncthreads();
      if (tid < H_){
        float gi = gtmp[tid], gf = gtmp[tid + H_], gg = gtmp[tid + 2*H_], go = gtmp[tid + 3*H_];
        float cn = fsig(gf) * c[tid] + fsig(gi) * ftanh(gg);
        float hn = fsig(go) * ftanh(cn);
        c[tid] = cn; h[tid] = hn;
        hh[dir][t][tid] = hn;
      }
      __syncthreads();
    }
  }

  for (int t = 0; t < T_; ++t){
    if (tid < OPS_ + 1){
      const float* wr = qlinW + tid * (2 * H_);
      float s = qlinb[tid];
      for (int k = 0; k < H_; ++k) s += wr[k] * hh[0][t][k];
      for (int k = 0; k < H_; ++k) s += wr[H_ + k] * hh[1][T_ - 1 - t][k];
      lg[tid] = s;
    }
    __syncthreads();
    if (tid == 0){
      float m = -1e30f;
      for (int o = 0; o < OPS_ + 1; ++o) m = fmaxf(m, lg[o]);
      float sum = 0.f;
      for (int o = 0; o < OPS_ + 1; ++o){ float e = __expf(lg[o] - m); lg[o] = e; sum += e; }
      float inv = frcp(sum);
      for (int o = 0; o < OPS_ + 1; ++o) lg[o] *= inv;
    }
    __syncthreads();
    if (tid < OPS_ + 1) query_attn[((size_t)(r * T_ + t) * B_ + b) * (OPS_ + 1) + tid] = lg[tid];
    __syncthreads();
  }
}

// ------------- entity input projection table: proj[dir][deg(25)][512] -------------
__global__ void eproj_kernel(const float* __restrict__ eemb, const float* __restrict__ eWih,
                             const float* __restrict__ ebih, const float* __restrict__ ebhh,
                             float* __restrict__ proj)
{
  int idx = blockIdx.x * 256 + threadIdx.x;
  if (idx >= 2 * (OPS_ + 1) * G4_) return;
  int j = idx % G4_;
  int v = (idx / G4_) % (OPS_ + 1);
  int dir = idx / (G4_ * (OPS_ + 1));
  const float4* wr = (const float4*)(eWih + (size_t)(dir * G4_ + j) * ED_);
  const float4* er = (const float4*)(eemb + v * ED_);
  float s = ebih[dir * G4_ + j] + ebhh[dir * G4_ + j];
  for (int k = 0; k < ED_ / 4; ++k){
    float4 wv = wr[k], ev = er[k];
    s += wv.x * ev.x + wv.y * ev.y + wv.z * ev.z + wv.w * ev.w;
  }
  proj[idx] = s;
}

// ---- build B-operand buffers in MFMA-fragment order ----
__global__ void wbuild_kernel(const float* __restrict__ eWhh, const float* __restrict__ proj,
                              u16* __restrict__ wtile, u16* __restrict__ wonehot)
{
  int idx = blockIdx.x * 256 + threadIdx.x;    // 2*32*5*64*8 = 163840
  if (idx >= 2 * 32 * 5 * 64 * 8) return;
  int jj = idx & 7;
  int lane = (idx >> 3) & 63;
  int kc = (idx >> 9) % 5;
  int gtile = (idx / (8 * 64 * 5)) & 31;
  int dir = idx / (8 * 64 * 5 * 32);
  int row = lane >> 4, col = lane & 15;
  int j = gtile * 16 + col;
  if (kc < 4){
    int k = kc * 32 + row * 8 + jj;
    float v = eWhh[((size_t)dir * G4_ + j) * H_ + k];
    wtile[((((size_t)dir * 32 + gtile) * 4 + kc) * 64 + lane) * 8 + jj] = (u16)f2bf(v);
  } else {
    int vdeg = row * 8 + jj;   // 0..31
    float v = (vdeg <= OPS_) ? proj[(size_t)dir * (OPS_ + 1) * G4_ + (size_t)vdeg * G4_ + j] : 0.f;
    wonehot[(((size_t)dir * 32 + gtile) * 64 + lane) * 8 + jj] = (u16)f2bf(v);
  }
}

// ------ entity BiLSTM: 512 threads, 8 waves, 64 entities (round-10 structure) ------
__global__ __launch_bounds__(512) void elstm_kernel(
    const int* __restrict__ degs,
    const u16* __restrict__ wtile, const u16* __restrict__ wonehot,
    u16* __restrict__ houts /* 2,N,128 bf16 */)
{
  int tid = threadIdx.x;
  int lane = tid & 63;
  int w = tid >> 6;        // wave 0..7
  int q = w >> 2;          // quad 0..1
  int wq = w & 3;          // h-slice owner within quad
  int row = lane >> 4, col = lane & 15;
  int ebase = blockIdx.x * 64;

  __shared__ __align__(16) short wlds[32 * 4 * 64 * 8];  // 128 KB
  __shared__ __align__(16) short hl[64 * HPAD];          // 21 KB

  int degr[MAXDEG_];
  {
    int eg = ebase + (tid & 63); if (eg >= N_) eg = N_ - 1;
    #pragma unroll
    for (int d = 0; d < MAXDEG_; ++d) degr[d] = degs[eg * MAXDEG_ + d];
  }

  {
    const float4* src = (const float4*)wtile;
    float4* dst = (float4*)wlds;
    for (int i = tid; i < 8192; i += 512) dst[i] = src[i];
  }
  for (int i = tid; i < 64 * HPAD; i += 512) hl[i] = 0;
  __syncthreads();
  if (tid < 64) hl[tid * HPAD + H_ + degr[0]] = BF16_ONE;   // dir0 first tt=0
  __syncthreads();

  for (int dir = 0; dir < 2; ++dir){
    const u16* Woh = wonehot + (size_t)dir * 32 * 64 * 8;
    float cst[16];
    #pragma unroll
    for (int i = 0; i < 16; ++i) cst[i] = 0.f;

    for (int t = 0; t < MAXDEG_; ++t){
      int tt = dir ? (MAXDEG_ - 1 - t) : t;
      f32x4 acc[16];
      #pragma unroll
      for (int i = 0; i < 16; ++i) acc[i] = (f32x4){0.f, 0.f, 0.f, 0.f};

      #pragma unroll 1
      for (int kc = 0; kc < 4; ++kc){
        bf16x8 af0 = *(const bf16x8*)&hl[(q * 32 + col) * HPAD + kc * 32 + row * 8];
        bf16x8 af1 = *(const bf16x8*)&hl[(q * 32 + 16 + col) * HPAD + kc * 32 + row * 8];
        #pragma unroll
        for (int g8 = 0; g8 < 8; ++g8){
          int gtile = (g8 >> 1) * 8 + wq * 2 + (g8 & 1);
          bf16x8 bfr = *(const bf16x8*)&wlds[((gtile * 4 + kc) * 64 + lane) * 8];
          acc[g8 * 2 + 0] = __builtin_amdgcn_mfma_f32_16x16x32_bf16(af0, bfr, acc[g8 * 2 + 0], 0, 0, 0);
          acc[g8 * 2 + 1] = __builtin_amdgcn_mfma_f32_16x16x32_bf16(af1, bfr, acc[g8 * 2 + 1], 0, 0, 0);
        }
      }
      {
        bf16x8 af0 = *(const bf16x8*)&hl[(q * 32 + col) * HPAD + H_ + row * 8];
        bf16x8 af1 = *(const bf16x8*)&hl[(q * 32 + 16 + col) * HPAD + H_ + row * 8];
        #pragma unroll
        for (int g8 = 0; g8 < 8; ++g8){
          int gtile = (g8 >> 1) * 8 + wq * 2 + (g8 & 1);
          bf16x8 bfr = *(const bf16x8*)(Woh + ((size_t)gtile * 64 + lane) * 8);
          acc[g8 * 2 + 0] = __builtin_amdgcn_mfma_f32_16x16x32_bf16(af0, bfr, acc[g8 * 2 + 0], 0, 0, 0);
          acc[g8 * 2 + 1] = __builtin_amdgcn_mfma_f32_16x16x32_bf16(af1, bfr, acc[g8 * 2 + 1], 0, 0, 0);
        }
      }

      __syncthreads();

      #pragma unroll
      for (int mt = 0; mt < 2; ++mt){
        #pragma unroll
        for (int reg = 0; reg < 4; ++reg){
          int e = q * 32 + mt * 16 + row * 4 + reg;
          #pragma unroll
          for (int gt2 = 0; gt2 < 2; ++gt2){
            int j = wq * 32 + gt2 * 16 + col;
            float gi = acc[(0 + gt2) * 2 + mt][reg];
            float gf = acc[(2 + gt2) * 2 + mt][reg];
            float gg = acc[(4 + gt2) * 2 + mt][reg];
            float go = acc[(6 + gt2) * 2 + mt][reg];
            int ci = (mt * 4 + reg) * 2 + gt2;
            float cn = fsig(gf) * cst[ci] + fsig(gi) * ftanh(gg);
            float hn = fsig(go) * ftanh(cn);
            cst[ci] = cn;
            hl[e * HPAD + j] = f2bf(hn);
          }
        }
      }
      if (tid < 64){
        hl[tid * HPAD + H_ + degr[tt]] = 0;
        if (t < MAXDEG_ - 1){
          int ttn = dir ? (MAXDEG_ - 2 - t) : (t + 1);
          hl[tid * HPAD + H_ + degr[ttn]] = BF16_ONE;
        }
      }
      __syncthreads();
    }

    for (int i = tid; i < 64 * H_; i += 512){
      int e = i >> 7, k = i & 127;
      int n = ebase + e;
      if (n < N_) houts[(size_t)dir * N_ * H_ + (size_t)n * H_ + k] = (u16)hl[e * HPAD + k];
    }
    if (dir == 0){
      __syncthreads();
      const float4* src = (const float4*)(wtile + (size_t)32 * 4 * 64 * 8);
      float4* dst = (float4*)wlds;
      for (int i = tid; i < 8192; i += 512) dst[i] = src[i];
      for (int i = tid; i < 64 * HPAD; i += 512) hl[i] = 0;
      __syncthreads();
      if (tid < 64) hl[tid * HPAD + H_ + degr[MAXDEG_ - 1]] = BF16_ONE;
      __syncthreads();
    }
  }
}

// ------------- entity attention: 10 entities x 24 ops per block, LDS-staged -------------
__global__ void eattn_kernel(const u16* __restrict__ hf, const u16* __restrict__ hb,
                             const float* __restrict__ elinW, const float* __restrict__ elinb,
                             float* __restrict__ attn /* N,24 */)
{
  __shared__ float W[OPS_][257];
  __shared__ float hhs[10][263];
  __shared__ float lgs[10][OPS_];
  int tid = threadIdx.x;    // 240
  int n0 = blockIdx.x * 10;
  for (int i = tid; i < OPS_ * 256; i += 240) W[i >> 8][i & 255] = elinW[i];
  for (int i = tid; i < 10 * H_; i += 240){
    int nl = i >> 7, k = i & 127;
    int n = n0 + nl;
    if (n < N_){
      hhs[nl][k]        = bf2f(hf[(size_t)n * H_ + k]);
      hhs[nl][H_ + k]   = bf2f(hb[(size_t)n * H_ + k]);
    }
  }
  __syncthreads();
  int nl = tid / OPS_;
  int o  = tid - nl * OPS_;
  int n  = n0 + nl;
  if (n < N_){
    float s = elinb[o];
    #pragma unroll 4
    for (int k = 0; k < 2 * H_; ++k) s += W[o][k] * hhs[nl][k];
    lgs[nl][o] = s;
  }
  __syncthreads();
  if (n < N_){
    float m = -1e30f;
    for (int i = 0; i < OPS_; ++i) m = fmaxf(m, lgs[nl][i]);
    float sum = 0.f;
    for (int i = 0; i < OPS_; ++i) sum += __expf(lgs[nl][i] - m);
    attn[(size_t)n * OPS_ + o] = __expf(lgs[nl][o] - m) * frcp(sum);
  }
}

// ---------------- CSR build: incoming-edge lists per node ----------------
__global__ void csr_count_kernel(const int* __restrict__ theads, const int* __restrict__ ttails,
                                 int* __restrict__ counts)
{
  int e = blockIdx.x * 256 + threadIdx.x;
  if (e < E_){
    atomicAdd(&counts[ttails[e]], 1);
    atomicAdd(&counts[theads[e]], 1);
  }
}

__global__ void csr_scan_kernel(const int* __restrict__ counts, int* __restrict__ rowptr,
                                int* __restrict__ cursor)
{
  __shared__ int lsum[1024];
  int t = threadIdx.x;
  const int CH = (N_ + 1023) / 1024;   // 49
  int base = t * CH;
  int s = 0;
  for (int i = 0; i < CH; ++i){
    int idx = base + i;
    if (idx < N_) s += counts[idx];
  }
  lsum[t] = s;
  __syncthreads();
  for (int o = 1; o < 1024; o <<= 1){
    int u = (t >= o) ? lsum[t - o] : 0;
    __syncthreads();
    lsum[t] += u;
    __syncthreads();
  }
  int run = lsum[t] - s;
  for (int i = 0; i < CH; ++i){
    int idx = base + i;
    if (idx < N_){
      rowptr[idx] = run;
      cursor[idx] = run;
      run += counts[idx];
    }
  }
  if (t == 1023) rowptr[N_] = run;
}

__global__ void csr_fill_kernel(const int* __restrict__ rels, const int* __restrict__ theads,
                                const int* __restrict__ ttails, const float* __restrict__ attn,
                                int* __restrict__ cursor, uint2* __restrict__ ents)
{
  int e = blockIdx.x * 256 + threadIdx.x;
  if (e < E_){
    int hh = theads[e], tt = ttails[e], rel = rels[e];
    float we = attn[(size_t)hh * OPS_ + rel];
    uint2 v1; v1.x = (unsigned)hh | ((unsigned)rel << 16);            v1.y = __float_as_uint(we);
    uint2 v2; v2.x = (unsigned)tt | ((unsigned)(rel + OPS_/2) << 16); v2.y = __float_as_uint(we);
    int p = atomicAdd(&cursor[tt], 1);
    ents[p] = v1;
    int qd = atomicAdd(&cursor[hh], 1);
    ents[qd] = v2;
  }
}

// ---------------- propagation (unnormalized u; scale-invariant) ----------------
__global__ void initu_kernel(const int* __restrict__ heads, float* __restrict__ u0)
{
  int idx = blockIdx.x * 256 + threadIdx.x;
  if (idx < N_ * B_){
    int b = idx & (B_ - 1);
    int n = idx >> 5;
    u0[idx] = (heads[b] == n) ? 1.0f : 0.0f;
  }
}

// atomic-free CSR gather, ONE WAVE PER NODE with pipelined edge processing.
// Halves (lanes 0-31 / 32-63) take alternate 4-entry chunks; each chunk issues
// 4 ent loads + 4 random ucur loads back-to-back (~8 outstanding misses/wave),
// fixing round-11's one-at-a-time dependent-load chain. Halves combine via
// shfl_xor(32). Fused row-sum partials. Zero atomics on u.
__global__ __launch_bounds__(256) void gather_kernel(
    const float* __restrict__ ucur, float* __restrict__ unxt,
    const float* __restrict__ qa, const int* __restrict__ rowptr,
    const uint2* __restrict__ ents, float* __restrict__ partial /* PSLOTS x B */)
{
  __shared__ float qas[B_ * (OPS_ + 1)];
  __shared__ float red[B_];
  int tid = threadIdx.x;
  for (int i = tid; i < B_ * (OPS_ + 1); i += 256) qas[i] = qa[i];
  if (tid < B_) red[tid] = 0.f;
  __syncthreads();
  int lane = tid & 63;
  int b = lane & 31;
  int h = lane >> 5;          // half 0/1
  int n = blockIdx.x * 4 + (tid >> 6);   // one wave per node; N = 12500*4 exactly
  float acc = 0.f;
  if (n < N_){
    int beg = rowptr[n], end = rowptr[n + 1];
    int cnt = end - beg;
    int nfull = cnt >> 2;
    if (h == 0) acc = ucur[(size_t)n * B_ + b] * qas[b * (OPS_ + 1) + OPS_];
    for (int c = h; c < nfull; c += 2){
      int i0 = beg + 4 * c;
      uint2 e0 = ents[i0 + 0];
      uint2 e1 = ents[i0 + 1];
      uint2 e2 = ents[i0 + 2];
      uint2 e3 = ents[i0 + 3];
      float u0 = ucur[(size_t)(e0.x & 0xFFFFu) * B_ + b];
      float u1 = ucur[(size_t)(e1.x & 0xFFFFu) * B_ + b];
      float u2 = ucur[(size_t)(e2.x & 0xFFFFu) * B_ + b];
      float u3 = ucur[(size_t)(e3.x & 0xFFFFu) * B_ + b];
      acc += qas[b * (OPS_ + 1) + (e0.x >> 16)] * __uint_as_float(e0.y) * u0;
      acc += qas[b * (OPS_ + 1) + (e1.x >> 16)] * __uint_as_float(e1.y) * u1;
      acc += qas[b * (OPS_ + 1) + (e2.x >> 16)] * __uint_as_float(e2.y) * u2;
      acc += qas[b * (OPS_ + 1) + (e3.x >> 16)] * __uint_as_float(e3.y) * u3;
    }
    if (h == 1){
      for (int i = beg + 4 * nfull; i < end; ++i){
        uint2 e0 = ents[i];
        acc += qas[b * (OPS_ + 1) + (e0.x >> 16)] * __uint_as_float(e0.y)
             * ucur[(size_t)(e0.x & 0xFFFFu) * B_ + b];
      }
    }
  }
  acc += __shfl_xor(acc, 32);
  if (n < N_ && h == 0){
    unxt[(size_t)n * B_ + b] = acc;
    atomicAdd(&red[b], acc);
  }
  __syncthreads();
  if (tid < B_) atomicAdd(&partial[(blockIdx.x & (PSLOTS - 1)) * B_ + tid], red[tid]);
}

// logacc += u / rowsum(u)   (rowsum from the PSLOTS partials of the last gather)
__global__ void finalize_kernel(float* __restrict__ logacc, const float* __restrict__ u,
                                const float* __restrict__ partial)
{
  __shared__ float smem[8][B_];
  __shared__ float sinv[B_];
  int tid = threadIdx.x;
  {
    int b = tid & (B_ - 1), pr = tid >> 5;
    float s = 0.f;
    #pragma unroll
    for (int k = 0; k < 8; ++k) s += partial[(pr + 8 * k) * B_ + b];
    smem[pr][b] = s;
  }
  __syncthreads();
  if (tid < B_){
    float s = 0.f;
    #pragma unroll
    for (int k = 0; k < 8; ++k) s += smem[k][tid];
    sinv[tid] = frcp(fmaxf(1e-20f, s));
  }
  __syncthreads();
  int idx = blockIdx.x * 256 + tid;
  if (idx < N_ * B_)
    logacc[idx] += u[idx] * sinv[idx & (B_ - 1)];
}

// ------------- final transpose: acc (N,B) -> out (B,N), LDS-tiled -------------
__global__ void transpose_kernel(const float* __restrict__ acc, float* __restrict__ out)
{
  __shared__ float t[B_][72];
  int n0 = blockIdx.x * 64;
  int tid = threadIdx.x;
  for (int i = tid; i < 64 * B_; i += 256){
    int nl = i >> 5, b = i & 31;
    int n = n0 + nl;
    t[b][nl] = (n < N_) ? acc[(size_t)n * B_ + b] : 0.f;
  }
  __syncthreads();
  for (int i = tid; i < 64 * B_; i += 256){
    int b = i >> 6, nl = i & 63;
    int n = n0 + nl;
    if (n < N_) out[(size_t)b * N_ + n] = t[b][nl];
  }
}

extern "C" void kernel_launch(void* const* d_in, const int* in_sizes, int n_in,
                              void* d_out, int out_size, void* d_ws, size_t ws_size,
                              hipStream_t stream)
{
  const int*   queries = (const int*)d_in[0];
  const int*   heads   = (const int*)d_in[1];
  const int*   rels    = (const int*)d_in[2];
  const int*   t_heads = (const int*)d_in[3];
  const int*   t_tails = (const int*)d_in[4];
  const int*   edeg    = (const int*)d_in[5];
  const float* qemb    = (const float*)d_in[6];
  const float* eemb    = (const float*)d_in[7];
  const float* qWih    = (const float*)d_in[8];
  const float* qWhh    = (const float*)d_in[9];
  const float* qbih    = (const float*)d_in[10];
  const float* qbhh    = (const float*)d_in[11];
  const float* eWih    = (const float*)d_in[12];
  const float* eWhh    = (const float*)d_in[13];
  const float* ebih    = (const float*)d_in[14];
  const float* ebhh    = (const float*)d_in[15];
  const float* qlinW   = (const float*)d_in[16];
  const float* qlinb   = (const float*)d_in[17];
  const float* elinW   = (const float*)d_in[18];
  const float* elinb   = (const float*)d_in[19];
  float* out = (float*)d_out;

  char* ws = (char*)d_ws;
  size_t off = 0;
  auto alloc = [&](size_t bytes){ void* p = ws + off; off += (bytes + 255) & ~(size_t)255; return p; };
  // region (25.6 MB): houts during [elstm, eattn]; then u0/u1/logacc (3x6.4 MB) +
  // ents (6.4 MB, written by csr_fill AFTER eattn) reuse the same bytes.
  char*  region     = (char*) alloc((size_t)2 * N_ * H_ * 2);                // 25.6 MB
  u16*   houts      = (u16*)region;
  float* mem0       = (float*)region;
  float* mem1       = (float*)(region + (size_t)N_ * B_ * 4);
  float* logacc     = (float*)(region + (size_t)2 * N_ * B_ * 4);
  uint2* ents       = (uint2*)(region + (size_t)3 * N_ * B_ * 4);            // 6.4 MB (=2E*8)
  float* query_attn = (float*)alloc((size_t)R_ * T_ * B_ * (OPS_ + 1) * 4);  //  29 KB
  float* proj       = (float*)alloc((size_t)2 * (OPS_ + 1) * G4_ * 4);       // 102 KB
  u16*   wtile      = (u16*)  alloc((size_t)2 * 32 * 4 * 64 * 8 * 2);        // 256 KB
  u16*   wonehot    = (u16*)  alloc((size_t)2 * 32 * 64 * 8 * 2);            //  64 KB
  float* attn       = (float*)alloc((size_t)N_ * OPS_ * 4);                  // 4.8 MB
  int*   counts     = (int*)  alloc((size_t)(N_ + 1) * 4);                   // 200 KB
  int*   rowptr     = (int*)  alloc((size_t)(N_ + 1) * 4);                   // 200 KB
  int*   cursor     = (int*)  alloc((size_t)(N_ + 1) * 4);                   // 200 KB
  float* sumsP      = (float*)alloc((size_t)R_ * T_ * PSLOTS * B_ * 4);      // 73 KB
  // total ~32 MB

  hipMemsetAsync(sumsP, 0, (size_t)R_ * T_ * PSLOTS * B_ * 4, stream);
  hipMemsetAsync(counts, 0, (size_t)(N_ + 1) * 4, stream);

  qattn_kernel<<<R_ * B_, 256, 0, stream>>>(queries, qemb, qWih, qWhh, qbih, qbhh,
                                            qlinW, qlinb, query_attn);
  eproj_kernel<<<(2 * (OPS_ + 1) * G4_ + 255) / 256, 256, 0, stream>>>(eemb, eWih, ebih, ebhh, proj);
  wbuild_kernel<<<(2 * 32 * 5 * 64 * 8 + 255) / 256, 256, 0, stream>>>(eWhh, proj, wtile, wonehot);
  csr_count_kernel<<<(E_ + 255) / 256, 256, 0, stream>>>(t_heads, t_tails, counts);
  csr_scan_kernel<<<1, 1024, 0, stream>>>(counts, rowptr, cursor);
  elstm_kernel<<<(N_ + 63) / 64, 512, 0, stream>>>(edeg, wtile, wonehot, houts);
  eattn_kernel<<<(N_ + 9) / 10, 240, 0, stream>>>(houts, houts + (size_t)N_ * H_,
                                                  elinW, elinb, attn);
  // houts dead; region reused for ents + propagation buffers
  csr_fill_kernel<<<(E_ + 255) / 256, 256, 0, stream>>>(rels, t_heads, t_tails, attn, cursor, ents);
  hipMemsetAsync(logacc, 0, (size_t)N_ * B_ * 4, stream);

  const int NB_BLK = (N_ * B_ + 255) / 256;
  const int GA_BLK = (N_ + 3) / 4;   // 12500: one wave per node
  for (int r = 0; r < R_; ++r){
    initu_kernel<<<NB_BLK, 256, 0, stream>>>(heads, mem0);
    float* cur = mem0;
    float* nxt = mem1;
    float* lastP = nullptr;
    for (int t = 0; t < T_; ++t){
      const float* qa = query_attn + (size_t)(r * T_ + t) * B_ * (OPS_ + 1);
      float* pslot = sumsP + (size_t)(r * T_ + t) * PSLOTS * B_;
      gather_kernel<<<GA_BLK, 256, 0, stream>>>(cur, nxt, qa, rowptr, ents, pslot);
      lastP = pslot;
      float* tmp = cur; cur = nxt; nxt = tmp;
    }
    finalize_kernel<<<NB_BLK, 256, 0, stream>>>(logacc, cur, lastP);
  }
  transpose_kernel<<<(N_ + 63) / 64, 256, 0, stream>>>(logacc, out);
}

// Round 13
// 1007.929 us; speedup vs baseline: 1.2924x; 1.1310x over previous
//
#include <hip/hip_runtime.h>

#define R_ 3
#define T_ 3
#define N_ 50000
#define OPS_ 24
#define E_ 400000
#define B_ 32
#define MAXDEG_ 8
#define QD_ 128
#define ED_ 128
#define H_ 128
#define G4_ (4*H_)   /* 512 */
#define HPAD 168     /* padded LDS h-row (bf16): 128 h + 25 one-hot + pad, 336 B */
#define PSLOTS 64    /* partial row-sum slots */
#define RB_ 96       /* 3 rounds x 32 batch */

typedef unsigned short u16;
typedef __attribute__((ext_vector_type(8))) short bf16x8;   // 8 bf16 = 4 VGPRs
typedef __attribute__((ext_vector_type(4))) float f32x4;

#define BF16_ONE ((short)0x3F80)

__device__ __forceinline__ short f2bf(float f){
  union { float f; unsigned u; } v; v.f = f;
  unsigned r = v.u + 0x7fffu + ((v.u >> 16) & 1u);
  return (short)(r >> 16);
}
__device__ __forceinline__ float bf2f(u16 u){
  union { unsigned u; float f; } v; v.u = ((unsigned)u) << 16; return v.f;
}
__device__ __forceinline__ float frcp(float x){ return __builtin_amdgcn_rcpf(x); }
__device__ __forceinline__ float fsig(float x){ return frcp(1.0f + __expf(-x)); }
// tanh(x) = 2*sigmoid(2x) - 1
__device__ __forceinline__ float ftanh(float x){
  return __builtin_fmaf(2.0f, fsig(2.0f * x), -1.0f);
}

// ---------------- query BiLSTM + attention: one block per (r,b) ----------------
__global__ void qattn_kernel(const int* __restrict__ queries, const float* __restrict__ qemb,
    const float* __restrict__ qWih, const float* __restrict__ qWhh,
    const float* __restrict__ qbih, const float* __restrict__ qbhh,
    const float* __restrict__ qlinW, const float* __restrict__ qlinb,
    float* __restrict__ query_attn /* R,T,B,25 */)
{
  int r = blockIdx.x / B_;
  int b = blockIdx.x % B_;
  int tid = threadIdx.x;   // 256
  __shared__ float x[QD_];
  __shared__ float gx[G4_];
  __shared__ float h[H_], c[H_];
  __shared__ float gtmp[G4_];
  __shared__ float hh[2][T_][H_];
  __shared__ float lg[OPS_ + 1];

  int q = queries[b];
  if (tid < QD_) x[tid] = qemb[q * QD_ + tid];
  __syncthreads();

  for (int dir = 0; dir < 2; ++dir){
    const float* Wih = qWih + (size_t)(r * 2 + dir) * G4_ * QD_;
    const float* Whh = qWhh + (size_t)(r * 2 + dir) * G4_ * H_;
    const float* bih = qbih + (r * 2 + dir) * G4_;
    const float* bhh = qbhh + (r * 2 + dir) * G4_;
    for (int j = tid; j < G4_; j += 256){
      const float4* wr = (const float4*)(Wih + (size_t)j * QD_);
      float s = bih[j] + bhh[j];
      for (int k = 0; k < QD_ / 4; ++k){
        float4 wv = wr[k];
        s += wv.x * x[4*k] + wv.y * x[4*k+1] + wv.z * x[4*k+2] + wv.w * x[4*k+3];
      }
      gx[j] = s;
    }
    if (tid < H_){ h[tid] = 0.f; c[tid] = 0.f; }
    __syncthreads();
    for (int t = 0; t < T_; ++t){
      for (int j = tid; j < G4_; j += 256){
        const float4* wr = (const float4*)(Whh + (size_t)j * H_);
        float s = 0.f;
        for (int k = 0; k < H_ / 4; ++k){
          float4 wv = wr[k];
          s += wv.x * h[4*k] + wv.y * h[4*k+1] + wv.z * h[4*k+2] + wv.w * h[4*k+3];
        }
        gtmp[j] = gx[j] + s;
      }
      __syncthreads();
      if (tid < H_){
        float gi = gtmp[tid], gf = gtmp[tid + H_], gg = gtmp[tid + 2*H_], go = gtmp[tid + 3*H_];
        float cn = fsig(gf) * c[tid] + fsig(gi) * ftanh(gg);
        float hn = fsig(go) * ftanh(cn);
        c[tid] = cn; h[tid] = hn;
        hh[dir][t][tid] = hn;
      }
      __syncthreads();
    }
  }

  for (int t = 0; t < T_; ++t){
    if (tid < OPS_ + 1){
      const float* wr = qlinW + tid * (2 * H_);
      float s = qlinb[tid];
      for (int k = 0; k < H_; ++k) s += wr[k] * hh[0][t][k];
      for (int k = 0; k < H_; ++k) s += wr[H_ + k] * hh[1][T_ - 1 - t][k];
      lg[tid] = s;
    }
    __syncthreads();
    if (tid == 0){
      float m = -1e30f;
      for (int o = 0; o < OPS_ + 1; ++o) m = fmaxf(m, lg[o]);
      float sum = 0.f;
      for (int o = 0; o < OPS_ + 1; ++o){ float e = __expf(lg[o] - m); lg[o] = e; sum += e; }
      float inv = frcp(sum);
      for (int o = 0; o < OPS_ + 1; ++o) lg[o] *= inv;
    }
    __syncthreads();
    if (tid < OPS_ + 1) query_attn[((size_t)(r * T_ + t) * B_ + b) * (OPS_ + 1) + tid] = lg[tid];
    __syncthreads();
  }
}

// ------------- entity input projection table: proj[dir][deg(25)][512] -------------
__global__ void eproj_kernel(const float* __restrict__ eemb, const float* __restrict__ eWih,
                             const float* __restrict__ ebih, const float* __restrict__ ebhh,
                             float* __restrict__ proj)
{
  int idx = blockIdx.x * 256 + threadIdx.x;
  if (idx >= 2 * (OPS_ + 1) * G4_) return;
  int j = idx % G4_;
  int v = (idx / G4_) % (OPS_ + 1);
  int dir = idx / (G4_ * (OPS_ + 1));
  const float4* wr = (const float4*)(eWih + (size_t)(dir * G4_ + j) * ED_);
  const float4* er = (const float4*)(eemb + v * ED_);
  float s = ebih[dir * G4_ + j] + ebhh[dir * G4_ + j];
  for (int k = 0; k < ED_ / 4; ++k){
    float4 wv = wr[k], ev = er[k];
    s += wv.x * ev.x + wv.y * ev.y + wv.z * ev.z + wv.w * ev.w;
  }
  proj[idx] = s;
}

// ---- build B-operand buffers in MFMA-fragment order ----
__global__ void wbuild_kernel(const float* __restrict__ eWhh, const float* __restrict__ proj,
                              u16* __restrict__ wtile, u16* __restrict__ wonehot)
{
  int idx = blockIdx.x * 256 + threadIdx.x;    // 2*32*5*64*8 = 163840
  if (idx >= 2 * 32 * 5 * 64 * 8) return;
  int jj = idx & 7;
  int lane = (idx >> 3) & 63;
  int kc = (idx >> 9) % 5;
  int gtile = (idx / (8 * 64 * 5)) & 31;
  int dir = idx / (8 * 64 * 5 * 32);
  int row = lane >> 4, col = lane & 15;
  int j = gtile * 16 + col;
  if (kc < 4){
    int k = kc * 32 + row * 8 + jj;
    float v = eWhh[((size_t)dir * G4_ + j) * H_ + k];
    wtile[((((size_t)dir * 32 + gtile) * 4 + kc) * 64 + lane) * 8 + jj] = (u16)f2bf(v);
  } else {
    int vdeg = row * 8 + jj;   // 0..31
    float v = (vdeg <= OPS_) ? proj[(size_t)dir * (OPS_ + 1) * G4_ + (size_t)vdeg * G4_ + j] : 0.f;
    wonehot[(((size_t)dir * 32 + gtile) * 64 + lane) * 8 + jj] = (u16)f2bf(v);
  }
}

// ------ entity BiLSTM: 512 threads, 8 waves, 64 entities (round-10 structure) ------
__global__ __launch_bounds__(512) void elstm_kernel(
    const int* __restrict__ degs,
    const u16* __restrict__ wtile, const u16* __restrict__ wonehot,
    u16* __restrict__ houts /* 2,N,128 bf16 */)
{
  int tid = threadIdx.x;
  int lane = tid & 63;
  int w = tid >> 6;        // wave 0..7
  int q = w >> 2;          // quad 0..1
  int wq = w & 3;          // h-slice owner within quad
  int row = lane >> 4, col = lane & 15;
  int ebase = blockIdx.x * 64;

  __shared__ __align__(16) short wlds[32 * 4 * 64 * 8];  // 128 KB
  __shared__ __align__(16) short hl[64 * HPAD];          // 21 KB

  int degr[MAXDEG_];
  {
    int eg = ebase + (tid & 63); if (eg >= N_) eg = N_ - 1;
    #pragma unroll
    for (int d = 0; d < MAXDEG_; ++d) degr[d] = degs[eg * MAXDEG_ + d];
  }

  {
    const float4* src = (const float4*)wtile;
    float4* dst = (float4*)wlds;
    for (int i = tid; i < 8192; i += 512) dst[i] = src[i];
  }
  for (int i = tid; i < 64 * HPAD; i += 512) hl[i] = 0;
  __syncthreads();
  if (tid < 64) hl[tid * HPAD + H_ + degr[0]] = BF16_ONE;   // dir0 first tt=0
  __syncthreads();

  for (int dir = 0; dir < 2; ++dir){
    const u16* Woh = wonehot + (size_t)dir * 32 * 64 * 8;
    float cst[16];
    #pragma unroll
    for (int i = 0; i < 16; ++i) cst[i] = 0.f;

    for (int t = 0; t < MAXDEG_; ++t){
      int tt = dir ? (MAXDEG_ - 1 - t) : t;
      f32x4 acc[16];
      #pragma unroll
      for (int i = 0; i < 16; ++i) acc[i] = (f32x4){0.f, 0.f, 0.f, 0.f};

      #pragma unroll 1
      for (int kc = 0; kc < 4; ++kc){
        bf16x8 af0 = *(const bf16x8*)&hl[(q * 32 + col) * HPAD + kc * 32 + row * 8];
        bf16x8 af1 = *(const bf16x8*)&hl[(q * 32 + 16 + col) * HPAD + kc * 32 + row * 8];
        #pragma unroll
        for (int g8 = 0; g8 < 8; ++g8){
          int gtile = (g8 >> 1) * 8 + wq * 2 + (g8 & 1);
          bf16x8 bfr = *(const bf16x8*)&wlds[((gtile * 4 + kc) * 64 + lane) * 8];
          acc[g8 * 2 + 0] = __builtin_amdgcn_mfma_f32_16x16x32_bf16(af0, bfr, acc[g8 * 2 + 0], 0, 0, 0);
          acc[g8 * 2 + 1] = __builtin_amdgcn_mfma_f32_16x16x32_bf16(af1, bfr, acc[g8 * 2 + 1], 0, 0, 0);
        }
      }
      {
        bf16x8 af0 = *(const bf16x8*)&hl[(q * 32 + col) * HPAD + H_ + row * 8];
        bf16x8 af1 = *(const bf16x8*)&hl[(q * 32 + 16 + col) * HPAD + H_ + row * 8];
        #pragma unroll
        for (int g8 = 0; g8 < 8; ++g8){
          int gtile = (g8 >> 1) * 8 + wq * 2 + (g8 & 1);
          bf16x8 bfr = *(const bf16x8*)(Woh + ((size_t)gtile * 64 + lane) * 8);
          acc[g8 * 2 + 0] = __builtin_amdgcn_mfma_f32_16x16x32_bf16(af0, bfr, acc[g8 * 2 + 0], 0, 0, 0);
          acc[g8 * 2 + 1] = __builtin_amdgcn_mfma_f32_16x16x32_bf16(af1, bfr, acc[g8 * 2 + 1], 0, 0, 0);
        }
      }

      __syncthreads();

      #pragma unroll
      for (int mt = 0; mt < 2; ++mt){
        #pragma unroll
        for (int reg = 0; reg < 4; ++reg){
          int e = q * 32 + mt * 16 + row * 4 + reg;
          #pragma unroll
          for (int gt2 = 0; gt2 < 2; ++gt2){
            int j = wq * 32 + gt2 * 16 + col;
            float gi = acc[(0 + gt2) * 2 + mt][reg];
            float gf = acc[(2 + gt2) * 2 + mt][reg];
            float gg = acc[(4 + gt2) * 2 + mt][reg];
            float go = acc[(6 + gt2) * 2 + mt][reg];
            int ci = (mt * 4 + reg) * 2 + gt2;
            float cn = fsig(gf) * cst[ci] + fsig(gi) * ftanh(gg);
            float hn = fsig(go) * ftanh(cn);
            cst[ci] = cn;
            hl[e * HPAD + j] = f2bf(hn);
          }
        }
      }
      if (tid < 64){
        hl[tid * HPAD + H_ + degr[tt]] = 0;
        if (t < MAXDEG_ - 1){
          int ttn = dir ? (MAXDEG_ - 2 - t) : (t + 1);
          hl[tid * HPAD + H_ + degr[ttn]] = BF16_ONE;
        }
      }
      __syncthreads();
    }

    for (int i = tid; i < 64 * H_; i += 512){
      int e = i >> 7, k = i & 127;
      int n = ebase + e;
      if (n < N_) houts[(size_t)dir * N_ * H_ + (size_t)n * H_ + k] = (u16)hl[e * HPAD + k];
    }
    if (dir == 0){
      __syncthreads();
      const float4* src = (const float4*)(wtile + (size_t)32 * 4 * 64 * 8);
      float4* dst = (float4*)wlds;
      for (int i = tid; i < 8192; i += 512) dst[i] = src[i];
      for (int i = tid; i < 64 * HPAD; i += 512) hl[i] = 0;
      __syncthreads();
      if (tid < 64) hl[tid * HPAD + H_ + degr[MAXDEG_ - 1]] = BF16_ONE;
      __syncthreads();
    }
  }
}

// ------------- entity attention: 10 entities x 24 ops per block, LDS-staged -------------
__global__ void eattn_kernel(const u16* __restrict__ hf, const u16* __restrict__ hb,
                             const float* __restrict__ elinW, const float* __restrict__ elinb,
                             float* __restrict__ attn /* N,24 */)
{
  __shared__ float W[OPS_][257];
  __shared__ float hhs[10][263];
  __shared__ float lgs[10][OPS_];
  int tid = threadIdx.x;    // 240
  int n0 = blockIdx.x * 10;
  for (int i = tid; i < OPS_ * 256; i += 240) W[i >> 8][i & 255] = elinW[i];
  for (int i = tid; i < 10 * H_; i += 240){
    int nl = i >> 7, k = i & 127;
    int n = n0 + nl;
    if (n < N_){
      hhs[nl][k]        = bf2f(hf[(size_t)n * H_ + k]);
      hhs[nl][H_ + k]   = bf2f(hb[(size_t)n * H_ + k]);
    }
  }
  __syncthreads();
  int nl = tid / OPS_;
  int o  = tid - nl * OPS_;
  int n  = n0 + nl;
  if (n < N_){
    float s = elinb[o];
    #pragma unroll 4
    for (int k = 0; k < 2 * H_; ++k) s += W[o][k] * hhs[nl][k];
    lgs[nl][o] = s;
  }
  __syncthreads();
  if (n < N_){
    float m = -1e30f;
    for (int i = 0; i < OPS_; ++i) m = fmaxf(m, lgs[nl][i]);
    float sum = 0.f;
    for (int i = 0; i < OPS_; ++i) sum += __expf(lgs[nl][i] - m);
    attn[(size_t)n * OPS_ + o] = __expf(lgs[nl][o] - m) * frcp(sum);
  }
}

// ---------------- CSR build: per-node in-edge AND out-edge lists ----------------
// Per fact (rel,h,t): in-list of t gets (src=h, rel); in-list of h gets (src=t, rel+12).
// Out-list of h gets (dst=t, rel); out-list of t gets (dst=h, rel+12).
// NOTE: in-degree == out-degree per node (each fact touches h and t once in both) ->
// one rowptr serves both CSRs.
__global__ void csr_count_kernel(const int* __restrict__ theads, const int* __restrict__ ttails,
                                 int* __restrict__ counts)
{
  int e = blockIdx.x * 256 + threadIdx.x;
  if (e < E_){
    atomicAdd(&counts[ttails[e]], 1);
    atomicAdd(&counts[theads[e]], 1);
  }
}

__global__ void csr_scan_kernel(const int* __restrict__ counts, int* __restrict__ rowptr,
                                int* __restrict__ cursor, int* __restrict__ cursor2)
{
  __shared__ int lsum[1024];
  int t = threadIdx.x;
  const int CH = (N_ + 1023) / 1024;   // 49
  int base = t * CH;
  int s = 0;
  for (int i = 0; i < CH; ++i){
    int idx = base + i;
    if (idx < N_) s += counts[idx];
  }
  lsum[t] = s;
  __syncthreads();
  for (int o = 1; o < 1024; o <<= 1){
    int u = (t >= o) ? lsum[t - o] : 0;
    __syncthreads();
    lsum[t] += u;
    __syncthreads();
  }
  int run = lsum[t] - s;
  for (int i = 0; i < CH; ++i){
    int idx = base + i;
    if (idx < N_){
      rowptr[idx] = run;
      cursor[idx] = run;
      cursor2[idx] = run;
      run += counts[idx];
    }
  }
  if (t == 1023) rowptr[N_] = run;
}

__global__ void csr_fill_kernel(const int* __restrict__ rels, const int* __restrict__ theads,
                                const int* __restrict__ ttails, const float* __restrict__ attn,
                                int* __restrict__ cursor, int* __restrict__ cursor2,
                                uint2* __restrict__ ents, uint2* __restrict__ ents2)
{
  int e = blockIdx.x * 256 + threadIdx.x;
  if (e < E_){
    int hh = theads[e], tt = ttails[e], rel = rels[e];
    unsigned wb = __float_as_uint(attn[(size_t)hh * OPS_ + rel]);
    uint2 v1; v1.x = (unsigned)hh | ((unsigned)rel << 16);            v1.y = wb;
    uint2 v2; v2.x = (unsigned)tt | ((unsigned)(rel + OPS_/2) << 16); v2.y = wb;
    ents[atomicAdd(&cursor[tt], 1)] = v1;
    ents[atomicAdd(&cursor[hh], 1)] = v2;
    uint2 w1; w1.x = (unsigned)tt | ((unsigned)rel << 16);            w1.y = wb;
    uint2 w2; w2.x = (unsigned)hh | ((unsigned)(rel + OPS_/2) << 16); w2.y = wb;
    ents2[atomicAdd(&cursor2[hh], 1)] = w1;
    ents2[atomicAdd(&cursor2[tt], 1)] = w2;
  }
}

// ---- t=0 sparse step: u0 is one-hot(heads) -> u1 from out-edges of 32 head nodes ----
// u1 pre-zeroed. Thread (r,b) owns column rb = r*32+b -> no write races, non-atomic +=.
__global__ void t0_kernel(const int* __restrict__ heads, const float* __restrict__ query_attn,
                          const int* __restrict__ rowptr, const uint2* __restrict__ ents2,
                          float* __restrict__ u1 /* N x 96 */)
{
  int tid = threadIdx.x;
  if (tid >= RB_) return;
  int r = tid >> 5, b = tid & 31;
  const float* qa = query_attn + ((size_t)(r * T_ + 0) * B_ + b) * (OPS_ + 1);
  int hn = heads[b];
  int rb = r * 32 + b;
  u1[(size_t)hn * RB_ + rb] += qa[OPS_];
  int beg = rowptr[hn], end = rowptr[hn + 1];
  for (int i = beg; i < end; ++i){
    uint2 e = ents2[i];
    int dst = (int)(e.x & 0xFFFFu);
    int rl  = (int)(e.x >> 16);
    u1[(size_t)dst * RB_ + rb] += qa[rl] * __uint_as_float(e.y);
  }
}

// ---- batched gather (3 rounds at once): half-wave per node, unroll-2 edges ----
// u layout [n][96]; rows are 384 B = 3 x 128 B segments -> all loads coalesced.
// 6 independent random u-loads in flight per iteration; zero atomics on u.
__global__ __launch_bounds__(256) void gather3_kernel(
    const float* __restrict__ ucur, float* __restrict__ unxt,
    const float* __restrict__ query_attn, int t,
    const int* __restrict__ rowptr, const uint2* __restrict__ ents,
    float* __restrict__ partial /* PSLOTS x 96 */)
{
  __shared__ float qas[3 * B_ * (OPS_ + 1)];  // [r][b][o]
  __shared__ float red[RB_];
  int tid = threadIdx.x;
  for (int i = tid; i < 3 * B_ * (OPS_ + 1); i += 256){
    int r = i / (B_ * (OPS_ + 1));
    int rem = i - r * (B_ * (OPS_ + 1));
    qas[i] = query_attn[(size_t)(r * T_ + t) * B_ * (OPS_ + 1) + rem];
  }
  if (tid < RB_) red[tid] = 0.f;
  __syncthreads();
  int b  = tid & 31;
  int hw = tid >> 5;                 // 0..7: node slot
  int n = blockIdx.x * 8 + hw;       // grid*8 == N_ exactly
  const float* q0 = &qas[0 * 800 + b * (OPS_ + 1)];
  const float* q1 = &qas[1 * 800 + b * (OPS_ + 1)];
  const float* q2 = &qas[2 * 800 + b * (OPS_ + 1)];
  size_t nb = (size_t)n * RB_;
  float a0 = ucur[nb + b]      * q0[OPS_];
  float a1 = ucur[nb + 32 + b] * q1[OPS_];
  float a2 = ucur[nb + 64 + b] * q2[OPS_];
  int beg = rowptr[n], end = rowptr[n + 1];
  int i = beg;
  for (; i + 1 < end; i += 2){
    uint2 e0 = ents[i], e1 = ents[i + 1];
    size_t s0 = (size_t)(e0.x & 0xFFFFu) * RB_;
    size_t s1 = (size_t)(e1.x & 0xFFFFu) * RB_;
    float u00 = ucur[s0 + b], u01 = ucur[s0 + 32 + b], u02 = ucur[s0 + 64 + b];
    float u10 = ucur[s1 + b], u11 = ucur[s1 + 32 + b], u12 = ucur[s1 + 64 + b];
    int r0 = (int)(e0.x >> 16), r1 = (int)(e1.x >> 16);
    float w0 = __uint_as_float(e0.y), w1 = __uint_as_float(e1.y);
    a0 += q0[r0] * w0 * u00 + q0[r1] * w1 * u10;
    a1 += q1[r0] * w0 * u01 + q1[r1] * w1 * u11;
    a2 += q2[r0] * w0 * u02 + q2[r1] * w1 * u12;
  }
  if (i < end){
    uint2 e0 = ents[i];
    size_t s0 = (size_t)(e0.x & 0xFFFFu) * RB_;
    int r0 = (int)(e0.x >> 16);
    float w0 = __uint_as_float(e0.y);
    a0 += q0[r0] * w0 * ucur[s0 + b];
    a1 += q1[r0] * w0 * ucur[s0 + 32 + b];
    a2 += q2[r0] * w0 * ucur[s0 + 64 + b];
  }
  unxt[nb + b]      = a0;
  unxt[nb + 32 + b] = a1;
  unxt[nb + 64 + b] = a2;
  atomicAdd(&red[b], a0);
  atomicAdd(&red[32 + b], a1);
  atomicAdd(&red[64 + b], a2);
  __syncthreads();
  if (tid < RB_)
    atomicAdd(&partial[(blockIdx.x & (PSLOTS - 1)) * RB_ + tid], red[tid]);
}

// ---- finalize + transpose: out[b][n] = sum_r u[n][r*32+b] / rowsum_r ----
__global__ void fintrans_kernel(const float* __restrict__ u, const float* __restrict__ partial,
                                float* __restrict__ out)
{
  __shared__ float sinv[RB_];
  __shared__ float t[B_][72];
  int tid = threadIdx.x;   // 256
  if (tid < RB_){
    float s = 0.f;
    #pragma unroll 8
    for (int k = 0; k < PSLOTS; ++k) s += partial[k * RB_ + tid];
    sinv[tid] = frcp(fmaxf(1e-20f, s));
  }
  __syncthreads();
  int n0 = blockIdx.x * 64;
  for (int i = tid; i < 64 * B_; i += 256){
    int nl = i >> 5, b = i & 31;
    int n = n0 + nl;
    float v = 0.f;
    if (n < N_){
      size_t nb = (size_t)n * RB_;
      v = u[nb + b] * sinv[b] + u[nb + 32 + b] * sinv[32 + b] + u[nb + 64 + b] * sinv[64 + b];
    }
    t[b][nl] = v;
  }
  __syncthreads();
  for (int i = tid; i < 64 * B_; i += 256){
    int b = i >> 6, nl = i & 63;
    int n = n0 + nl;
    if (n < N_) out[(size_t)b * N_ + n] = t[b][nl];
  }
}

extern "C" void kernel_launch(void* const* d_in, const int* in_sizes, int n_in,
                              void* d_out, int out_size, void* d_ws, size_t ws_size,
                              hipStream_t stream)
{
  const int*   queries = (const int*)d_in[0];
  const int*   heads   = (const int*)d_in[1];
  const int*   rels    = (const int*)d_in[2];
  const int*   t_heads = (const int*)d_in[3];
  const int*   t_tails = (const int*)d_in[4];
  const int*   edeg    = (const int*)d_in[5];
  const float* qemb    = (const float*)d_in[6];
  const float* eemb    = (const float*)d_in[7];
  const float* qWih    = (const float*)d_in[8];
  const float* qWhh    = (const float*)d_in[9];
  const float* qbih    = (const float*)d_in[10];
  const float* qbhh    = (const float*)d_in[11];
  const float* eWih    = (const float*)d_in[12];
  const float* eWhh    = (const float*)d_in[13];
  const float* ebih    = (const float*)d_in[14];
  const float* ebhh    = (const float*)d_in[15];
  const float* qlinW   = (const float*)d_in[16];
  const float* qlinb   = (const float*)d_in[17];
  const float* elinW   = (const float*)d_in[18];
  const float* elinb   = (const float*)d_in[19];
  float* out = (float*)d_out;

  char* ws = (char*)d_ws;
  size_t off = 0;
  auto alloc = [&](size_t bytes){ void* p = ws + off; off += (bytes + 255) & ~(size_t)255; return p; };
  // bigA (25.6 MB): houts during [elstm, eattn]; after eattn dead ->
  //   ents (6.4 MB, csr_fill) at +0, u0 (19.2 MB, written by gather t1) at +6.4 MB.
  char*  bigA  = (char*)alloc((size_t)2 * N_ * H_ * 2);               // 25,600,000
  u16*   houts = (u16*)bigA;
  uint2* ents  = (uint2*)bigA;                                        // 2E*8 = 6,400,000
  float* u0    = (float*)(bigA + (size_t)2 * E_ * 8);                 // N*96*4 = 19,200,000
  // bigB (19.2 MB): attn (4.8 MB) during [eattn, csr_fill]; then u1 (memset after fill).
  char*  bigB  = (char*)alloc((size_t)N_ * RB_ * 4);
  float* attn  = (float*)bigB;
  float* u1    = (float*)bigB;
  uint2* ents2      = (uint2*)alloc((size_t)2 * E_ * 8);              // 6.4 MB
  float* query_attn = (float*)alloc((size_t)R_ * T_ * B_ * (OPS_ + 1) * 4);
  float* proj       = (float*)alloc((size_t)2 * (OPS_ + 1) * G4_ * 4);
  u16*   wtile      = (u16*)  alloc((size_t)2 * 32 * 4 * 64 * 8 * 2);
  u16*   wonehot    = (u16*)  alloc((size_t)2 * 32 * 64 * 8 * 2);
  int*   counts     = (int*)  alloc((size_t)(N_ + 1) * 4);
  int*   rowptr     = (int*)  alloc((size_t)(N_ + 1) * 4);
  int*   cursor     = (int*)  alloc((size_t)(N_ + 1) * 4);
  int*   cursor2    = (int*)  alloc((size_t)(N_ + 1) * 4);
  float* sumsP      = (float*)alloc((size_t)2 * PSLOTS * RB_ * 4);    // slots for t1, t2
  // total ~53 MB

  hipMemsetAsync(sumsP, 0, (size_t)2 * PSLOTS * RB_ * 4, stream);
  hipMemsetAsync(counts, 0, (size_t)(N_ + 1) * 4, stream);

  qattn_kernel<<<R_ * B_, 256, 0, stream>>>(queries, qemb, qWih, qWhh, qbih, qbhh,
                                            qlinW, qlinb, query_attn);
  eproj_kernel<<<(2 * (OPS_ + 1) * G4_ + 255) / 256, 256, 0, stream>>>(eemb, eWih, ebih, ebhh, proj);
  wbuild_kernel<<<(2 * 32 * 5 * 64 * 8 + 255) / 256, 256, 0, stream>>>(eWhh, proj, wtile, wonehot);
  csr_count_kernel<<<(E_ + 255) / 256, 256, 0, stream>>>(t_heads, t_tails, counts);
  csr_scan_kernel<<<1, 1024, 0, stream>>>(counts, rowptr, cursor, cursor2);
  elstm_kernel<<<(N_ + 63) / 64, 512, 0, stream>>>(edeg, wtile, wonehot, houts);
  eattn_kernel<<<(N_ + 9) / 10, 240, 0, stream>>>(houts, houts + (size_t)N_ * H_,
                                                  elinW, elinb, attn);
  // houts dead -> ents may overwrite bigA; attn still live (read here):
  csr_fill_kernel<<<(E_ + 255) / 256, 256, 0, stream>>>(rels, t_heads, t_tails, attn,
                                                        cursor, cursor2, ents, ents2);
  // attn dead -> u1 takes bigB
  hipMemsetAsync(u1, 0, (size_t)N_ * RB_ * 4, stream);
  t0_kernel<<<1, 128, 0, stream>>>(heads, query_attn, rowptr, ents2, u1);
  const int GA_BLK = N_ / 8;   // 6250
  gather3_kernel<<<GA_BLK, 256, 0, stream>>>(u1, u0, query_attn, 1, rowptr, ents,
                                             sumsP + 0 * PSLOTS * RB_);
  gather3_kernel<<<GA_BLK, 256, 0, stream>>>(u0, u1, query_attn, 2, rowptr, ents,
                                             sumsP + 1 * PSLOTS * RB_);
  fintrans_kernel<<<(N_ + 63) / 64, 256, 0, stream>>>(u1, sumsP + 1 * PSLOTS * RB_, out);
}

// Round 15
// 959.498 us; speedup vs baseline: 1.3576x; 1.0505x over previous
//
#include <hip/hip_runtime.h>

#define R_ 3
#define T_ 3
#define N_ 50000
#define OPS_ 24
#define E_ 400000
#define B_ 32
#define MAXDEG_ 8
#define QD_ 128
#define ED_ 128
#define H_ 128
#define G4_ (4*H_)   /* 512 */
#define HPAD 168     /* padded LDS h-row (bf16): 128 h + 25 one-hot + pad, 336 B */
#define PSLOTS 64    /* partial row-sum slots */
#define RB_ 96       /* 3 rounds x 32 batch */

typedef unsigned short u16;
typedef __attribute__((ext_vector_type(8))) short bf16x8;   // 8 bf16 = 4 VGPRs
typedef __attribute__((ext_vector_type(4))) float f32x4;

#define BF16_ONE ((short)0x3F80)

__device__ __forceinline__ short f2bf(float f){
  union { float f; unsigned u; } v; v.f = f;
  unsigned r = v.u + 0x7fffu + ((v.u >> 16) & 1u);
  return (short)(r >> 16);
}
__device__ __forceinline__ float bf2f(u16 u){
  union { unsigned u; float f; } v; v.u = ((unsigned)u) << 16; return v.f;
}
__device__ __forceinline__ float frcp(float x){ return __builtin_amdgcn_rcpf(x); }
__device__ __forceinline__ float fsig(float x){ return frcp(1.0f + __expf(-x)); }
// tanh(x) = 2*sigmoid(2x) - 1
__device__ __forceinline__ float ftanh(float x){
  return __builtin_fmaf(2.0f, fsig(2.0f * x), -1.0f);
}

// ---------------- query BiLSTM + attention: one block per (r,b) ----------------
__global__ void qattn_kernel(const int* __restrict__ queries, const float* __restrict__ qemb,
    const float* __restrict__ qWih, const float* __restrict__ qWhh,
    const float* __restrict__ qbih, const float* __restrict__ qbhh,
    const float* __restrict__ qlinW, const float* __restrict__ qlinb,
    float* __restrict__ query_attn /* R,T,B,25 */)
{
  int r = blockIdx.x / B_;
  int b = blockIdx.x % B_;
  int tid = threadIdx.x;   // 256
  __shared__ float x[QD_];
  __shared__ float gx[G4_];
  __shared__ float h[H_], c[H_];
  __shared__ float gtmp[G4_];
  __shared__ float hh[2][T_][H_];
  __shared__ float lg[OPS_ + 1];

  int q = queries[b];
  if (tid < QD_) x[tid] = qemb[q * QD_ + tid];
  __syncthreads();

  for (int dir = 0; dir < 2; ++dir){
    const float* Wih = qWih + (size_t)(r * 2 + dir) * G4_ * QD_;
    const float* Whh = qWhh + (size_t)(r * 2 + dir) * G4_ * H_;
    const float* bih = qbih + (r * 2 + dir) * G4_;
    const float* bhh = qbhh + (r * 2 + dir) * G4_;
    for (int j = tid; j < G4_; j += 256){
      const float4* wr = (const float4*)(Wih + (size_t)j * QD_);
      float s = bih[j] + bhh[j];
      for (int k = 0; k < QD_ / 4; ++k){
        float4 wv = wr[k];
        s += wv.x * x[4*k] + wv.y * x[4*k+1] + wv.z * x[4*k+2] + wv.w * x[4*k+3];
      }
      gx[j] = s;
    }
    if (tid < H_){ h[tid] = 0.f; c[tid] = 0.f; }
    __syncthreads();
    for (int t = 0; t < T_; ++t){
      for (int j = tid; j < G4_; j += 256){
        const float4* wr = (const float4*)(Whh + (size_t)j * H_);
        float s = 0.f;
        for (int k = 0; k < H_ / 4; ++k){
          float4 wv = wr[k];
          s += wv.x * h[4*k] + wv.y * h[4*k+1] + wv.z * h[4*k+2] + wv.w * h[4*k+3];
        }
        gtmp[j] = gx[j] + s;
      }
      __syncthreads();
      if (tid < H_){
        float gi = gtmp[tid], gf = gtmp[tid + H_], gg = gtmp[tid + 2*H_], go = gtmp[tid + 3*H_];
        float cn = fsig(gf) * c[tid] + fsig(gi) * ftanh(gg);
        float hn = fsig(go) * ftanh(cn);
        c[tid] = cn; h[tid] = hn;
        hh[dir][t][tid] = hn;
      }
      __syncthreads();
    }
  }

  for (int t = 0; t < T_; ++t){
    if (tid < OPS_ + 1){
      const float* wr = qlinW + tid * (2 * H_);
      float s = qlinb[tid];
      for (int k = 0; k < H_; ++k) s += wr[k] * hh[0][t][k];
      for (int k = 0; k < H_; ++k) s += wr[H_ + k] * hh[1][T_ - 1 - t][k];
      lg[tid] = s;
    }
    __syncthreads();
    if (tid == 0){
      float m = -1e30f;
      for (int o = 0; o < OPS_ + 1; ++o) m = fmaxf(m, lg[o]);
      float sum = 0.f;
      for (int o = 0; o < OPS_ + 1; ++o){ float e = __expf(lg[o] - m); lg[o] = e; sum += e; }
      float inv = frcp(sum);
      for (int o = 0; o < OPS_ + 1; ++o) lg[o] *= inv;
    }
    __syncthreads();
    if (tid < OPS_ + 1) query_attn[((size_t)(r * T_ + t) * B_ + b) * (OPS_ + 1) + tid] = lg[tid];
    __syncthreads();
  }
}

// ---- build B-operand buffers in MFMA-fragment order (eproj folded in) ----
__global__ void wbuild_kernel(const float* __restrict__ eWhh,
                              const float* __restrict__ eemb, const float* __restrict__ eWih,
                              const float* __restrict__ ebih, const float* __restrict__ ebhh,
                              u16* __restrict__ wtile, u16* __restrict__ wonehot)
{
  int idx = blockIdx.x * 256 + threadIdx.x;    // 2*32*5*64*8 = 163840
  if (idx >= 2 * 32 * 5 * 64 * 8) return;
  int jj = idx & 7;
  int lane = (idx >> 3) & 63;
  int kc = (idx >> 9) % 5;
  int gtile = (idx / (8 * 64 * 5)) & 31;
  int dir = idx / (8 * 64 * 5 * 32);
  int row = lane >> 4, col = lane & 15;
  int j = gtile * 16 + col;
  if (kc < 4){
    int k = kc * 32 + row * 8 + jj;
    float v = eWhh[((size_t)dir * G4_ + j) * H_ + k];
    wtile[((((size_t)dir * 32 + gtile) * 4 + kc) * 64 + lane) * 8 + jj] = (u16)f2bf(v);
  } else {
    int vdeg = row * 8 + jj;   // 0..31
    float v = 0.f;
    if (vdeg <= OPS_){
      const float4* wr = (const float4*)(eWih + (size_t)(dir * G4_ + j) * ED_);
      const float4* er = (const float4*)(eemb + (size_t)vdeg * ED_);
      float s = ebih[dir * G4_ + j] + ebhh[dir * G4_ + j];
      for (int k = 0; k < ED_ / 4; ++k){
        float4 wv = wr[k], ev = er[k];
        s += wv.x * ev.x + wv.y * ev.y + wv.z * ev.z + wv.w * ev.w;
      }
      v = s;
    }
    wonehot[(((size_t)dir * 32 + gtile) * 64 + lane) * 8 + jj] = (u16)f2bf(v);
  }
}

// ------ entity BiLSTM: 512 threads, 8 waves, 64 entities (round-10 structure) ------
__global__ __launch_bounds__(512) void elstm_kernel(
    const int* __restrict__ degs,
    const u16* __restrict__ wtile, const u16* __restrict__ wonehot,
    u16* __restrict__ houts /* 2,N,128 bf16 */)
{
  int tid = threadIdx.x;
  int lane = tid & 63;
  int w = tid >> 6;        // wave 0..7
  int q = w >> 2;          // quad 0..1
  int wq = w & 3;          // h-slice owner within quad
  int row = lane >> 4, col = lane & 15;
  int ebase = blockIdx.x * 64;

  __shared__ __align__(16) short wlds[32 * 4 * 64 * 8];  // 128 KB
  __shared__ __align__(16) short hl[64 * HPAD];          // 21 KB

  int degr[MAXDEG_];
  {
    int eg = ebase + (tid & 63); if (eg >= N_) eg = N_ - 1;
    #pragma unroll
    for (int d = 0; d < MAXDEG_; ++d) degr[d] = degs[eg * MAXDEG_ + d];
  }

  {
    const float4* src = (const float4*)wtile;
    float4* dst = (float4*)wlds;
    for (int i = tid; i < 8192; i += 512) dst[i] = src[i];
  }
  for (int i = tid; i < 64 * HPAD; i += 512) hl[i] = 0;
  __syncthreads();
  if (tid < 64) hl[tid * HPAD + H_ + degr[0]] = BF16_ONE;   // dir0 first tt=0
  __syncthreads();

  for (int dir = 0; dir < 2; ++dir){
    const u16* Woh = wonehot + (size_t)dir * 32 * 64 * 8;
    float cst[16];
    #pragma unroll
    for (int i = 0; i < 16; ++i) cst[i] = 0.f;

    for (int t = 0; t < MAXDEG_; ++t){
      int tt = dir ? (MAXDEG_ - 1 - t) : t;
      f32x4 acc[16];
      #pragma unroll
      for (int i = 0; i < 16; ++i) acc[i] = (f32x4){0.f, 0.f, 0.f, 0.f};

      #pragma unroll 1
      for (int kc = 0; kc < 4; ++kc){
        bf16x8 af0 = *(const bf16x8*)&hl[(q * 32 + col) * HPAD + kc * 32 + row * 8];
        bf16x8 af1 = *(const bf16x8*)&hl[(q * 32 + 16 + col) * HPAD + kc * 32 + row * 8];
        #pragma unroll
        for (int g8 = 0; g8 < 8; ++g8){
          int gtile = (g8 >> 1) * 8 + wq * 2 + (g8 & 1);
          bf16x8 bfr = *(const bf16x8*)&wlds[((gtile * 4 + kc) * 64 + lane) * 8];
          acc[g8 * 2 + 0] = __builtin_amdgcn_mfma_f32_16x16x32_bf16(af0, bfr, acc[g8 * 2 + 0], 0, 0, 0);
          acc[g8 * 2 + 1] = __builtin_amdgcn_mfma_f32_16x16x32_bf16(af1, bfr, acc[g8 * 2 + 1], 0, 0, 0);
        }
      }
      {
        bf16x8 af0 = *(const bf16x8*)&hl[(q * 32 + col) * HPAD + H_ + row * 8];
        bf16x8 af1 = *(const bf16x8*)&hl[(q * 32 + 16 + col) * HPAD + H_ + row * 8];
        #pragma unroll
        for (int g8 = 0; g8 < 8; ++g8){
          int gtile = (g8 >> 1) * 8 + wq * 2 + (g8 & 1);
          bf16x8 bfr = *(const bf16x8*)(Woh + ((size_t)gtile * 64 + lane) * 8);
          acc[g8 * 2 + 0] = __builtin_amdgcn_mfma_f32_16x16x32_bf16(af0, bfr, acc[g8 * 2 + 0], 0, 0, 0);
          acc[g8 * 2 + 1] = __builtin_amdgcn_mfma_f32_16x16x32_bf16(af1, bfr, acc[g8 * 2 + 1], 0, 0, 0);
        }
      }

      __syncthreads();

      #pragma unroll
      for (int mt = 0; mt < 2; ++mt){
        #pragma unroll
        for (int reg = 0; reg < 4; ++reg){
          int e = q * 32 + mt * 16 + row * 4 + reg;
          #pragma unroll
          for (int gt2 = 0; gt2 < 2; ++gt2){
            int j = wq * 32 + gt2 * 16 + col;
            float gi = acc[(0 + gt2) * 2 + mt][reg];
            float gf = acc[(2 + gt2) * 2 + mt][reg];
            float gg = acc[(4 + gt2) * 2 + mt][reg];
            float go = acc[(6 + gt2) * 2 + mt][reg];
            int ci = (mt * 4 + reg) * 2 + gt2;
            float cn = fsig(gf) * cst[ci] + fsig(gi) * ftanh(gg);
            float hn = fsig(go) * ftanh(cn);
            cst[ci] = cn;
            hl[e * HPAD + j] = f2bf(hn);
          }
        }
      }
      if (tid < 64){
        hl[tid * HPAD + H_ + degr[tt]] = 0;
        if (t < MAXDEG_ - 1){
          int ttn = dir ? (MAXDEG_ - 2 - t) : (t + 1);
          hl[tid * HPAD + H_ + degr[ttn]] = BF16_ONE;
        }
      }
      __syncthreads();
    }

    for (int i = tid; i < 64 * H_; i += 512){
      int e = i >> 7, k = i & 127;
      int n = ebase + e;
      if (n < N_) houts[(size_t)dir * N_ * H_ + (size_t)n * H_ + k] = (u16)hl[e * HPAD + k];
    }
    if (dir == 0){
      __syncthreads();
      const float4* src = (const float4*)(wtile + (size_t)32 * 4 * 64 * 8);
      float4* dst = (float4*)wlds;
      for (int i = tid; i < 8192; i += 512) dst[i] = src[i];
      for (int i = tid; i < 64 * HPAD; i += 512) hl[i] = 0;
      __syncthreads();
      if (tid < 64) hl[tid * HPAD + H_ + degr[MAXDEG_ - 1]] = BF16_ONE;
      __syncthreads();
    }
  }
}

// ------------- entity attention: 10 entities x 24 ops per block, LDS-staged -------------
__global__ void eattn_kernel(const u16* __restrict__ hf, const u16* __restrict__ hb,
                             const float* __restrict__ elinW, const float* __restrict__ elinb,
                             float* __restrict__ attn /* N,24 */)
{
  __shared__ float W[OPS_][257];
  __shared__ float hhs[10][263];
  __shared__ float lgs[10][OPS_];
  int tid = threadIdx.x;    // 240
  int n0 = blockIdx.x * 10;
  for (int i = tid; i < OPS_ * 256; i += 240) W[i >> 8][i & 255] = elinW[i];
  for (int i = tid; i < 10 * H_; i += 240){
    int nl = i >> 7, k = i & 127;
    int n = n0 + nl;
    if (n < N_){
      hhs[nl][k]        = bf2f(hf[(size_t)n * H_ + k]);
      hhs[nl][H_ + k]   = bf2f(hb[(size_t)n * H_ + k]);
    }
  }
  __syncthreads();
  int nl = tid / OPS_;
  int o  = tid - nl * OPS_;
  int n  = n0 + nl;
  if (n < N_){
    float s = elinb[o];
    #pragma unroll 4
    for (int k = 0; k < 2 * H_; ++k) s += W[o][k] * hhs[nl][k];
    lgs[nl][o] = s;
  }
  __syncthreads();
  if (n < N_){
    float m = -1e30f;
    for (int i = 0; i < OPS_; ++i) m = fmaxf(m, lgs[nl][i]);
    float sum = 0.f;
    for (int i = 0; i < OPS_; ++i) sum += __expf(lgs[nl][i] - m);
    attn[(size_t)n * OPS_ + o] = __expf(lgs[nl][o] - m) * frcp(sum);
  }
}

// ---------------- CSR build: per-node in-edge AND out-edge lists ----------------
__global__ void csr_count_kernel(const int* __restrict__ theads, const int* __restrict__ ttails,
                                 int* __restrict__ counts)
{
  int e = blockIdx.x * 256 + threadIdx.x;
  if (e < E_){
    atomicAdd(&counts[ttails[e]], 1);
    atomicAdd(&counts[theads[e]], 1);
  }
}

__global__ void csr_scan_kernel(const int* __restrict__ counts, int* __restrict__ rowptr,
                                int* __restrict__ cursor, int* __restrict__ cursor2)
{
  __shared__ int lsum[1024];
  int t = threadIdx.x;
  const int CH = (N_ + 1023) / 1024;   // 49
  int base = t * CH;
  int s = 0;
  for (int i = 0; i < CH; ++i){
    int idx = base + i;
    if (idx < N_) s += counts[idx];
  }
  lsum[t] = s;
  __syncthreads();
  for (int o = 1; o < 1024; o <<= 1){
    int u = (t >= o) ? lsum[t - o] : 0;
    __syncthreads();
    lsum[t] += u;
    __syncthreads();
  }
  int run = lsum[t] - s;
  for (int i = 0; i < CH; ++i){
    int idx = base + i;
    if (idx < N_){
      rowptr[idx] = run;
      cursor[idx] = run;
      cursor2[idx] = run;
      run += counts[idx];
    }
  }
  if (t == 1023) rowptr[N_] = run;
}

__global__ void csr_fill_kernel(const int* __restrict__ rels, const int* __restrict__ theads,
                                const int* __restrict__ ttails, const float* __restrict__ attn,
                                int* __restrict__ cursor, int* __restrict__ cursor2,
                                uint2* __restrict__ ents, uint2* __restrict__ ents2)
{
  int e = blockIdx.x * 256 + threadIdx.x;
  if (e < E_){
    int hh = theads[e], tt = ttails[e], rel = rels[e];
    unsigned wb = __float_as_uint(attn[(size_t)hh * OPS_ + rel]);
    uint2 v1; v1.x = (unsigned)hh | ((unsigned)rel << 16);            v1.y = wb;
    uint2 v2; v2.x = (unsigned)tt | ((unsigned)(rel + OPS_/2) << 16); v2.y = wb;
    ents[atomicAdd(&cursor[tt], 1)] = v1;
    ents[atomicAdd(&cursor[hh], 1)] = v2;
    uint2 w1; w1.x = (unsigned)tt | ((unsigned)rel << 16);            w1.y = wb;
    uint2 w2; w2.x = (unsigned)hh | ((unsigned)(rel + OPS_/2) << 16); w2.y = wb;
    ents2[atomicAdd(&cursor2[hh], 1)] = w1;
    ents2[atomicAdd(&cursor2[tt], 1)] = w2;
  }
}

// ---- t=0 sparse step: u0 is one-hot(heads) -> u1 from out-edges of 32 head nodes ----
__global__ void t0_kernel(const int* __restrict__ heads, const float* __restrict__ query_attn,
                          const int* __restrict__ rowptr, const uint2* __restrict__ ents2,
                          float* __restrict__ u1 /* N x 96 */)
{
  int tid = threadIdx.x;
  if (tid >= RB_) return;
  int r = tid >> 5, b = tid & 31;
  const float* qa = query_attn + ((size_t)(r * T_ + 0) * B_ + b) * (OPS_ + 1);
  int hn = heads[b];
  int rb = r * 32 + b;
  u1[(size_t)hn * RB_ + rb] += qa[OPS_];
  int beg = rowptr[hn], end = rowptr[hn + 1];
  for (int i = beg; i < end; ++i){
    uint2 e = ents2[i];
    int dst = (int)(e.x & 0xFFFFu);
    int rl  = (int)(e.x >> 16);
    u1[(size_t)dst * RB_ + rb] += qa[rl] * __uint_as_float(e.y);
  }
}

// ---- t=1 dense self-term: u2 = qa1_24 (.) u1 (elementwise; replaces memset) ----
__global__ void u2init_kernel(const float* __restrict__ query_attn,
                              const float* __restrict__ u1, float* __restrict__ u2)
{
  __shared__ float q24[RB_];
  int tid = threadIdx.x;
  if (tid < RB_){
    int r = tid >> 5, b = tid & 31;
    q24[tid] = query_attn[((size_t)(r * T_ + 1) * B_ + b) * (OPS_ + 1) + OPS_];
  }
  __syncthreads();
  int idx = blockIdx.x * 256 + tid;
  if (idx < N_ * RB_) u2[idx] = u1[idx] * q24[idx % RB_];
}

// ---- t=1 sparse pushes: u1 nonzero only at {head} U outNbr(head) per column.
// Per-path 2-hop formulation; head's self-mass outflow is the single-hop term.
__global__ void t1push_kernel(const int* __restrict__ heads, const float* __restrict__ query_attn,
                              const int* __restrict__ rowptr, const uint2* __restrict__ ents2,
                              const float* __restrict__ u1, float* __restrict__ u2)
{
  __shared__ float qa0[OPS_ + 1], qa1[OPS_ + 1];
  int blk = blockIdx.x;   // 0..95
  int r = blk >> 5, b = blk & 31;
  int rb = r * 32 + b;
  int tid = threadIdx.x;  // 64
  if (tid < OPS_ + 1){
    qa0[tid] = query_attn[((size_t)(r * T_ + 0) * B_ + b) * (OPS_ + 1) + tid];
    qa1[tid] = query_attn[((size_t)(r * T_ + 1) * B_ + b) * (OPS_ + 1) + tid];
  }
  __syncthreads();
  int hd = heads[b];
  int beg = rowptr[hd], end = rowptr[hd + 1];
  float q024 = qa0[OPS_];
  for (int i = beg + tid; i < end; i += 64){
    uint2 e1 = ents2[i];
    int s  = (int)(e1.x & 0xFFFFu);
    int r1 = (int)(e1.x >> 16);
    float w1 = __uint_as_float(e1.y);
    atomicAdd(&u2[(size_t)s * RB_ + rb], qa1[r1] * w1 * q024);
    float v1 = qa0[r1] * w1;      // this path's share of u1[s]
    int b2 = rowptr[s], e2e = rowptr[s + 1];
    for (int jj = b2; jj < e2e; ++jj){
      uint2 e2 = ents2[jj];
      int d2 = (int)(e2.x & 0xFFFFu);
      int r2 = (int)(e2.x >> 16);
      atomicAdd(&u2[(size_t)d2 * RB_ + rb], qa1[r2] * __uint_as_float(e2.y) * v1);
    }
  }
}

// ---- batched dense gather (t=2): ONE WAVE per node, halves split 4-edge chunks ----
// 12 independent random u-loads + 4 ent loads in flight per half; halves combine
// via shfl_xor(32) -- same wave, same node (r14 bug: 8 nodes/block mixed waves).
__global__ __launch_bounds__(256) void gather3_kernel(
    const float* __restrict__ ucur, float* __restrict__ unxt,
    const float* __restrict__ query_attn, int t,
    const int* __restrict__ rowptr, const uint2* __restrict__ ents,
    float* __restrict__ partial /* PSLOTS x 96 */)
{
  __shared__ float qas[3 * B_ * (OPS_ + 1)];  // [r][b][o]
  __shared__ float red[RB_];
  int tid = threadIdx.x;
  for (int i = tid; i < 3 * B_ * (OPS_ + 1); i += 256){
    int r = i / (B_ * (OPS_ + 1));
    int rem = i - r * (B_ * (OPS_ + 1));
    qas[i] = query_attn[(size_t)(r * T_ + t) * B_ * (OPS_ + 1) + rem];
  }
  if (tid < RB_) red[tid] = 0.f;
  __syncthreads();
  int b  = tid & 31;
  int h  = (tid >> 5) & 1;              // half within wave
  int n = blockIdx.x * 4 + (tid >> 6);  // one wave per node; grid*4 == N_
  const float* q0 = &qas[0 * 800 + b * (OPS_ + 1)];
  const float* q1 = &qas[1 * 800 + b * (OPS_ + 1)];
  const float* q2 = &qas[2 * 800 + b * (OPS_ + 1)];
  size_t nb = (size_t)n * RB_;
  float a0 = 0.f, a1 = 0.f, a2 = 0.f;
  if (h == 0){
    a0 = ucur[nb + b]      * q0[OPS_];
    a1 = ucur[nb + 32 + b] * q1[OPS_];
    a2 = ucur[nb + 64 + b] * q2[OPS_];
  }
  int beg = rowptr[n], end = rowptr[n + 1];
  int cnt = end - beg;
  int nq = cnt >> 2;                 // full 4-edge chunks
  for (int c = h; c < nq; c += 2){
    int i0 = beg + 4 * c;
    uint2 e0 = ents[i0 + 0];
    uint2 e1 = ents[i0 + 1];
    uint2 e2 = ents[i0 + 2];
    uint2 e3 = ents[i0 + 3];
    size_t s0 = (size_t)(e0.x & 0xFFFFu) * RB_;
    size_t s1 = (size_t)(e1.x & 0xFFFFu) * RB_;
    size_t s2 = (size_t)(e2.x & 0xFFFFu) * RB_;
    size_t s3 = (size_t)(e3.x & 0xFFFFu) * RB_;
    float u00 = ucur[s0 + b], u01 = ucur[s0 + 32 + b], u02 = ucur[s0 + 64 + b];
    float u10 = ucur[s1 + b], u11 = ucur[s1 + 32 + b], u12 = ucur[s1 + 64 + b];
    float u20 = ucur[s2 + b], u21 = ucur[s2 + 32 + b], u22 = ucur[s2 + 64 + b];
    float u30 = ucur[s3 + b], u31 = ucur[s3 + 32 + b], u32 = ucur[s3 + 64 + b];
    int r0 = (int)(e0.x >> 16), r1 = (int)(e1.x >> 16);
    int r2 = (int)(e2.x >> 16), r3 = (int)(e3.x >> 16);
    float w0 = __uint_as_float(e0.y), w1 = __uint_as_float(e1.y);
    float w2 = __uint_as_float(e2.y), w3 = __uint_as_float(e3.y);
    a0 += q0[r0]*w0*u00 + q0[r1]*w1*u10 + q0[r2]*w2*u20 + q0[r3]*w3*u30;
    a1 += q1[r0]*w0*u01 + q1[r1]*w1*u11 + q1[r2]*w2*u21 + q1[r3]*w3*u31;
    a2 += q2[r0]*w0*u02 + q2[r1]*w1*u12 + q2[r2]*w2*u22 + q2[r3]*w3*u32;
  }
  if (h == 1){
    for (int i = beg + 4 * nq; i < end; ++i){
      uint2 e0 = ents[i];
      size_t s0 = (size_t)(e0.x & 0xFFFFu) * RB_;
      int r0 = (int)(e0.x >> 16);
      float w0 = __uint_as_float(e0.y);
      a0 += q0[r0] * w0 * ucur[s0 + b];
      a1 += q1[r0] * w0 * ucur[s0 + 32 + b];
      a2 += q2[r0] * w0 * ucur[s0 + 64 + b];
    }
  }
  a0 += __shfl_xor(a0, 32);
  a1 += __shfl_xor(a1, 32);
  a2 += __shfl_xor(a2, 32);
  if (h == 0){
    unxt[nb + b]      = a0;
    unxt[nb + 32 + b] = a1;
    unxt[nb + 64 + b] = a2;
    atomicAdd(&red[b], a0);
    atomicAdd(&red[32 + b], a1);
    atomicAdd(&red[64 + b], a2);
  }
  __syncthreads();
  if (tid < RB_)
    atomicAdd(&partial[(blockIdx.x & (PSLOTS - 1)) * RB_ + tid], red[tid]);
}

// ---- finalize + transpose: out[b][n] = sum_r u[n][r*32+b] / rowsum_r ----
__global__ void fintrans_kernel(const float* __restrict__ u, const float* __restrict__ partial,
                                float* __restrict__ out)
{
  __shared__ float sinv[RB_];
  __shared__ float t[B_][72];
  int tid = threadIdx.x;   // 256
  if (tid < RB_){
    float s = 0.f;
    #pragma unroll 8
    for (int k = 0; k < PSLOTS; ++k) s += partial[k * RB_ + tid];
    sinv[tid] = frcp(fmaxf(1e-20f, s));
  }
  __syncthreads();
  int n0 = blockIdx.x * 64;
  for (int i = tid; i < 64 * B_; i += 256){
    int nl = i >> 5, b = i & 31;
    int n = n0 + nl;
    float v = 0.f;
    if (n < N_){
      size_t nb = (size_t)n * RB_;
      v = u[nb + b] * sinv[b] + u[nb + 32 + b] * sinv[32 + b] + u[nb + 64 + b] * sinv[64 + b];
    }
    t[b][nl] = v;
  }
  __syncthreads();
  for (int i = tid; i < 64 * B_; i += 256){
    int b = i >> 6, nl = i & 63;
    int n = n0 + nl;
    if (n < N_) out[(size_t)b * N_ + n] = t[b][nl];
  }
}

extern "C" void kernel_launch(void* const* d_in, const int* in_sizes, int n_in,
                              void* d_out, int out_size, void* d_ws, size_t ws_size,
                              hipStream_t stream)
{
  const int*   queries = (const int*)d_in[0];
  const int*   heads   = (const int*)d_in[1];
  const int*   rels    = (const int*)d_in[2];
  const int*   t_heads = (const int*)d_in[3];
  const int*   t_tails = (const int*)d_in[4];
  const int*   edeg    = (const int*)d_in[5];
  const float* qemb    = (const float*)d_in[6];
  const float* eemb    = (const float*)d_in[7];
  const float* qWih    = (const float*)d_in[8];
  const float* qWhh    = (const float*)d_in[9];
  const float* qbih    = (const float*)d_in[10];
  const float* qbhh    = (const float*)d_in[11];
  const float* eWih    = (const float*)d_in[12];
  const float* eWhh    = (const float*)d_in[13];
  const float* ebih    = (const float*)d_in[14];
  const float* ebhh    = (const float*)d_in[15];
  const float* qlinW   = (const float*)d_in[16];
  const float* qlinb   = (const float*)d_in[17];
  const float* elinW   = (const float*)d_in[18];
  const float* elinb   = (const float*)d_in[19];
  float* out = (float*)d_out;

  char* ws = (char*)d_ws;
  size_t off = 0;
  auto alloc = [&](size_t bytes){ void* p = ws + off; off += (bytes + 255) & ~(size_t)255; return p; };
  // bigA (25.6 MB): houts during [elstm, eattn]; after eattn dead ->
  //   ents (6.4 MB, csr_fill) at +0, u2 (19.2 MB) at +6.4 MB.
  char*  bigA  = (char*)alloc((size_t)2 * N_ * H_ * 2);               // 25,600,000
  u16*   houts = (u16*)bigA;
  uint2* ents  = (uint2*)bigA;                                        // in-CSR, 6.4 MB
  float* u2    = (float*)(bigA + (size_t)2 * E_ * 8);                 // 19.2 MB
  // bigB (19.2 MB): attn (4.8 MB) during [eattn, csr_fill]; then u1; then u3.
  char*  bigB  = (char*)alloc((size_t)N_ * RB_ * 4);
  float* attn  = (float*)bigB;
  float* u1    = (float*)bigB;
  float* u3    = (float*)bigB;
  uint2* ents2      = (uint2*)alloc((size_t)2 * E_ * 8);              // out-CSR, 6.4 MB
  float* query_attn = (float*)alloc((size_t)R_ * T_ * B_ * (OPS_ + 1) * 4);
  u16*   wtile      = (u16*)  alloc((size_t)2 * 32 * 4 * 64 * 8 * 2);
  u16*   wonehot    = (u16*)  alloc((size_t)2 * 32 * 64 * 8 * 2);
  int*   counts     = (int*)  alloc((size_t)(N_ + 1) * 4);
  int*   rowptr     = (int*)  alloc((size_t)(N_ + 1) * 4);
  int*   cursor     = (int*)  alloc((size_t)(N_ + 1) * 4);
  int*   cursor2    = (int*)  alloc((size_t)(N_ + 1) * 4);
  float* sumsP      = (float*)alloc((size_t)PSLOTS * RB_ * 4);        // t2 partials only
  // total ~52 MB

  hipMemsetAsync(sumsP, 0, (size_t)PSLOTS * RB_ * 4, stream);
  hipMemsetAsync(counts, 0, (size_t)(N_ + 1) * 4, stream);

  qattn_kernel<<<R_ * B_, 256, 0, stream>>>(queries, qemb, qWih, qWhh, qbih, qbhh,
                                            qlinW, qlinb, query_attn);
  wbuild_kernel<<<(2 * 32 * 5 * 64 * 8 + 255) / 256, 256, 0, stream>>>(
      eWhh, eemb, eWih, ebih, ebhh, wtile, wonehot);
  csr_count_kernel<<<(E_ + 255) / 256, 256, 0, stream>>>(t_heads, t_tails, counts);
  csr_scan_kernel<<<1, 1024, 0, stream>>>(counts, rowptr, cursor, cursor2);
  elstm_kernel<<<(N_ + 63) / 64, 512, 0, stream>>>(edeg, wtile, wonehot, houts);
  eattn_kernel<<<(N_ + 9) / 10, 240, 0, stream>>>(houts, houts + (size_t)N_ * H_,
                                                  elinW, elinb, attn);
  // houts dead -> ents may take bigA[0:6.4M]; attn still live (read by csr_fill):
  csr_fill_kernel<<<(E_ + 255) / 256, 256, 0, stream>>>(rels, t_heads, t_tails, attn,
                                                        cursor, cursor2, ents, ents2);
  // attn dead -> u1 takes bigB
  hipMemsetAsync(u1, 0, (size_t)N_ * RB_ * 4, stream);
  t0_kernel<<<1, 128, 0, stream>>>(heads, query_attn, rowptr, ents2, u1);
  // t=1: dense self-term + sparse 2-hop pushes (replaces a full dense gather)
  u2init_kernel<<<(N_ * RB_ + 255) / 256, 256, 0, stream>>>(query_attn, u1, u2);
  t1push_kernel<<<RB_, 64, 0, stream>>>(heads, query_attn, rowptr, ents2, u1, u2);
  // t=2: dense gather (u1 dead; u3 overwrites bigB)
  gather3_kernel<<<N_ / 4, 256, 0, stream>>>(u2, u3, query_attn, 2, rowptr, ents, sumsP);
  fintrans_kernel<<<(N_ + 63) / 64, 256, 0, stream>>>(u3, sumsP, out);
}